// Round 3
// baseline (303.349 us; speedup 1.0000x reference)
//
#include <hip/hip_runtime.h>
#include <math.h>

#define HD 256
#define SD 768
#define D2 512
#define NE 8
#define NB 32
#define NBLK 256
#define NTHR 256

__device__ __forceinline__ float gelu_exact(float x) {
    return 0.5f * x * (1.0f + erff(x * 0.70710678118654752f));
}

// Init-agnostic grid barrier: per-barrier slot array, per-launch token.
// Block b publishes tok to slots[b]; thread t spins on slots[t].
__device__ __forceinline__ void gsync(unsigned* slots, unsigned tok) {
    __syncthreads();
    __threadfence();   // publish this block's global writes at device scope
    if (threadIdx.x == 0)
        __hip_atomic_store(slots + blockIdx.x, tok, __ATOMIC_RELEASE,
                           __HIP_MEMORY_SCOPE_AGENT);
    for (;;) {
        unsigned v = __hip_atomic_load(slots + threadIdx.x, __ATOMIC_ACQUIRE,
                                       __HIP_MEMORY_SCOPE_AGENT);
        if (v == tok) break;
        __builtin_amdgcn_s_sleep(4);
    }
    __threadfence();
    __syncthreads();
}

// Shared-memory carve-up (floats): big staging buffer + W tile + reduce + small
#define S_BIG   0        // 32*520 = 16640  (E1/E2 staging; P0 s_in; P1 s_p/s_v/s_f2)
#define S_W     16640    // 128*16 = 2048
#define S_RED   18688    // 256
#define S_SMALL 18944    // 16
#define SMEM_F  18960    // 75,840 B -> 2 blocks/CU capacity

__global__ __launch_bounds__(256) void fused_all(
    const float* __restrict__ smiles,
    const float* __restrict__ sW, const float* __restrict__ sb,
    const float* __restrict__ Wv, const float* __restrict__ bv,
    const float* __restrict__ Wo, const float* __restrict__ bo,
    const float* __restrict__ gW, const float* __restrict__ gb,
    const float* __restrict__ W1, const float* __restrict__ b1,
    const float* __restrict__ W2, const float* __restrict__ b2,
    const float* __restrict__ lng, const float* __restrict__ lnb,
    const float* __restrict__ clsW, const float* __restrict__ clsb,
    float* __restrict__ proj, float* __restrict__ fused,
    float* __restrict__ probs, float* __restrict__ pn,
    int* __restrict__ sel, float* __restrict__ h1,
    float* __restrict__ eo, unsigned* __restrict__ slots,
    unsigned* __restrict__ LC, float* __restrict__ out)
{
    __shared__ __align__(16) float smem[SMEM_F];
    __shared__ unsigned s_lc;
    const int bid = blockIdx.x, t = threadIdx.x;

    if (t == 0)
        s_lc = __hip_atomic_load(LC, __ATOMIC_ACQUIRE, __HIP_MEMORY_SCOPE_AGENT);
    __syncthreads();
    const unsigned tb = s_lc * 2654435761u;

    // ---------------- P0: proj = smiles @ sW + sb (256 blocks) ----------------
    {
        int r = bid >> 3, sl = bid & 7;
        float* s_in = smem + S_BIG;                 // 768
        float* s_red = smem + S_RED;
        const float* srow = smiles + (size_t)r * SD;
        for (int i = t; i < SD / 4; i += NTHR)
            ((float4*)s_in)[i] = ((const float4*)srow)[i];
        __syncthreads();
        int c = t & 31, kq = t >> 5;                // 32 cols x 8 k-quadrants
        float acc = 0.f;
        const float* wp = sW + (size_t)(kq * 96) * HD + sl * 32 + c;
        #pragma unroll 8
        for (int k = 0; k < 96; ++k)
            acc = fmaf(s_in[kq * 96 + k], wp[(size_t)k * HD], acc);
        s_red[t] = acc;
        __syncthreads();
        if (t < 32) {
            float s = 0.f;
            #pragma unroll
            for (int q = 0; q < 8; ++q) s += s_red[q * 32 + t];
            int col = sl * 32 + t;
            s += sb[col];
            proj[r * HD + col] = s;
            fused[(size_t)r * 2 * HD + HD + col] = s;   // second half = proj
        }
    }
    gsync(slots + 0 * NBLK, tb + 1u);

    // ---------------- P1: v -> attended -> gate/top2 (32 blocks) --------------
    if (bid < NB) {
        int b = bid;
        float* s_p  = smem + S_BIG;          // 256
        float* s_v  = smem + S_BIG + 256;    // 256
        float* s_f2 = smem + S_BIG + 512;    // 512
        float* s_red = smem + S_RED;
        float* s_gate = smem + S_SMALL;
        for (int i = t; i < HD; i += NTHR) s_p[i] = proj[b * HD + i];
        __syncthreads();
        float vv = bv[t];
        #pragma unroll 16
        for (int k = 0; k < HD; ++k) vv = fmaf(s_p[k], Wv[(size_t)k * HD + t], vv);
        s_v[t] = vv;
        __syncthreads();
        float att = bo[t];
        #pragma unroll 16
        for (int k = 0; k < HD; ++k) att = fmaf(s_v[k], Wo[(size_t)k * HD + t], att);
        s_f2[t] = att;
        s_f2[HD + t] = s_p[t];
        fused[(size_t)b * 2 * HD + t] = att;
        __syncthreads();

        int e = t & 7, ch = t >> 3;
        float gp = 0.f;
        #pragma unroll
        for (int j = 0; j < 16; ++j) {
            int d = ch * 16 + j;
            gp = fmaf(s_f2[d], gW[d * NE + e], gp);
        }
        s_red[t] = gp;
        __syncthreads();
        for (int off = 128; off >= 8; off >>= 1) {
            if (t < off) s_red[t] += s_red[t + off];
            __syncthreads();
        }
        if (t < NE) s_gate[t] = s_red[t] + gb[t];
        __syncthreads();
        if (t == 0) {
            float m = s_gate[0];
            for (int i = 1; i < NE; ++i) m = fmaxf(m, s_gate[i]);
            float ex[NE], ssum = 0.f;
            for (int i = 0; i < NE; ++i) { ex[i] = expf(s_gate[i] - m); ssum += ex[i]; }
            float pr[NE];
            for (int i = 0; i < NE; ++i) { pr[i] = ex[i] / ssum; probs[b * NE + i] = pr[i]; }
            int i1 = 0;
            for (int i = 1; i < NE; ++i) if (pr[i] > pr[i1]) i1 = i;
            int i2 = (i1 == 0) ? 1 : 0;
            for (int i = 0; i < NE; ++i) if (i != i1 && pr[i] > pr[i2]) i2 = i;
            float p1 = pr[i1], p2 = pr[i2], s12 = p1 + p2;
            sel[b * 2 + 0] = i1;
            sel[b * 2 + 1] = i2;
            pn[b * 2 + 0] = p1 / s12;
            pn[b * 2 + 1] = p2 / s12;
        }
    }
    gsync(slots + 1 * NBLK, tb + 2u);

    // ---------------- P2: h1 = gelu(fused @ W1[e] + b1[e]) (256 blocks) -------
    {
        int e = bid >> 5, ct = bid & 31;
        float* s_f = smem + S_BIG;    // [32][520]
        float* s_w = smem + S_W;      // [128][16]
        for (int i = t; i < NB * D2 / 4; i += NTHR) {
            int row = i >> 7, f = i & 127;
            *(float4*)&s_f[row * 520 + f * 4] = ((const float4*)fused)[i];
        }
        int c = t & 15, rg = t >> 4, r0 = rg * 2, r1 = r0 + 1;
        float a0 = 0.f, a1 = 0.f, a2 = 0.f, a3 = 0.f;
        const float* W = W1 + (size_t)e * D2 * D2 + ct * 16;
        for (int k0 = 0; k0 < D2; k0 += 128) {
            __syncthreads();
            for (int i = t; i < 128 * 4; i += NTHR) {
                int kk = i >> 2, f = i & 3;
                *(float4*)&s_w[kk * 16 + f * 4] =
                    *(const float4*)(W + (size_t)(k0 + kk) * D2 + f * 4);
            }
            __syncthreads();
            #pragma unroll 8
            for (int kk = 0; kk < 128; kk += 2) {
                float w0 = s_w[kk * 16 + c], w1 = s_w[(kk + 1) * 16 + c];
                a0 = fmaf(s_f[r0 * 520 + k0 + kk], w0, a0);
                a1 = fmaf(s_f[r0 * 520 + k0 + kk + 1], w1, a1);
                a2 = fmaf(s_f[r1 * 520 + k0 + kk], w0, a2);
                a3 = fmaf(s_f[r1 * 520 + k0 + kk + 1], w1, a3);
            }
        }
        int col = ct * 16 + c;
        float bias = b1[e * D2 + col];
        h1[((size_t)e * NB + r0) * D2 + col] = gelu_exact(a0 + a1 + bias);
        h1[((size_t)e * NB + r1) * D2 + col] = gelu_exact(a2 + a3 + bias);
    }
    gsync(slots + 2 * NBLK, tb + 3u);

    // ---------------- P3: eo = h1 @ W2[e] + b2[e] (128 blocks) ----------------
    if (bid < 128) {
        int e = bid >> 4, ct = bid & 15;
        float* s_h = smem + S_BIG;
        float* s_w = smem + S_W;
        const float4* src = (const float4*)(h1 + (size_t)e * NB * D2);
        for (int i = t; i < NB * D2 / 4; i += NTHR) {
            int row = i >> 7, f = i & 127;
            *(float4*)&s_h[row * 520 + f * 4] = src[i];
        }
        int c = t & 15, rg = t >> 4, r0 = rg * 2, r1 = r0 + 1;
        float a0 = 0.f, a1 = 0.f, a2 = 0.f, a3 = 0.f;
        const float* W = W2 + (size_t)e * D2 * HD + ct * 16;
        for (int k0 = 0; k0 < D2; k0 += 128) {
            __syncthreads();
            for (int i = t; i < 128 * 4; i += NTHR) {
                int kk = i >> 2, f = i & 3;
                *(float4*)&s_w[kk * 16 + f * 4] =
                    *(const float4*)(W + (size_t)(k0 + kk) * HD + f * 4);
            }
            __syncthreads();
            #pragma unroll 8
            for (int kk = 0; kk < 128; kk += 2) {
                float w0 = s_w[kk * 16 + c], w1 = s_w[(kk + 1) * 16 + c];
                a0 = fmaf(s_h[r0 * 520 + k0 + kk], w0, a0);
                a1 = fmaf(s_h[r0 * 520 + k0 + kk + 1], w1, a1);
                a2 = fmaf(s_h[r1 * 520 + k0 + kk], w0, a2);
                a3 = fmaf(s_h[r1 * 520 + k0 + kk + 1], w1, a3);
            }
        }
        int col = ct * 16 + c;
        float bias = b2[e * HD + col];
        eo[((size_t)e * NB + r0) * HD + col] = a0 + a1 + bias;
        eo[((size_t)e * NB + r1) * HD + col] = a2 + a3 + bias;
    }
    gsync(slots + 3 * NBLK, tb + 4u);

    // launch-token bump: safe — every block already read LC before barrier 1
    if (bid == 0 && t == 0)
        __hip_atomic_store(LC, s_lc + 1u, __ATOMIC_RELEASE, __HIP_MEMORY_SCOPE_AGENT);

    // ---------------- P4: gather/combine, LN, classifier, aux (32 blocks) -----
    if (bid < NB) {
        int b = bid;
        float* s_red = smem + S_RED;
        float* s_stats = smem + S_SMALL;
        int e0 = sel[b * 2 + 0], e1 = sel[b * 2 + 1];
        float p0 = pn[b * 2 + 0], p1 = pn[b * 2 + 1];
        float moe = p0 * eo[((size_t)e0 * NB + b) * HD + t]
                  + p1 * eo[((size_t)e1 * NB + b) * HD + t];

        s_red[t] = moe; __syncthreads();
        for (int off = 128; off > 0; off >>= 1) {
            if (t < off) s_red[t] += s_red[t + off];
            __syncthreads();
        }
        if (t == 0) s_stats[0] = s_red[0] * (1.f / HD);
        __syncthreads();
        float mu = s_stats[0];
        float d = moe - mu;

        s_red[t] = d * d; __syncthreads();
        for (int off = 128; off > 0; off >>= 1) {
            if (t < off) s_red[t] += s_red[t + off];
            __syncthreads();
        }
        if (t == 0) s_stats[1] = s_red[0] * (1.f / HD);
        __syncthreads();

        float xn = d * rsqrtf(s_stats[1] + 1e-5f);
        float y = fmaf(xn, lng[t], lnb[t]);

        s_red[t] = y * clsW[t * 2 + 0]; __syncthreads();
        for (int off = 128; off > 0; off >>= 1) {
            if (t < off) s_red[t] += s_red[t + off];
            __syncthreads();
        }
        if (t == 0) s_stats[2] = s_red[0] + clsb[0];
        __syncthreads();

        s_red[t] = y * clsW[t * 2 + 1]; __syncthreads();
        for (int off = 128; off > 0; off >>= 1) {
            if (t < off) s_red[t] += s_red[t + off];
            __syncthreads();
        }
        if (t == 0) {
            out[b * 2 + 0] = s_stats[2];
            out[b * 2 + 1] = s_red[0] + clsb[1];
        }

        if (bid == 0) {
            __syncthreads();
            s_red[t] = probs[t];
            __syncthreads();
            for (int off = 128; off >= 8; off >>= 1) {
                if (t < off) s_red[t] += s_red[t + off];
                __syncthreads();
            }
            if (t == 0) {
                float aux = 0.f;
                for (int e = 0; e < NE; ++e) {
                    float u = s_red[e] * (1.f / 32.f);
                    aux += u * logf(0.125f) - logf(u) * 0.125f;
                }
                out[64] = 0.1f * aux;
            }
        }
    }
}

extern "C" void kernel_launch(void* const* d_in, const int* in_sizes, int n_in,
                              void* d_out, int out_size, void* d_ws, size_t ws_size,
                              hipStream_t stream) {
    (void)in_sizes; (void)n_in; (void)out_size; (void)ws_size;
    const float* smiles = (const float*)d_in[2];
    const float* sW  = (const float*)d_in[7];
    const float* sb  = (const float*)d_in[8];
    const float* Wv  = (const float*)d_in[13];
    const float* bv  = (const float*)d_in[14];
    const float* Wo  = (const float*)d_in[15];
    const float* bo  = (const float*)d_in[16];
    const float* gW  = (const float*)d_in[17];
    const float* gb  = (const float*)d_in[18];
    const float* W1  = (const float*)d_in[19];
    const float* b1  = (const float*)d_in[20];
    const float* W2  = (const float*)d_in[21];
    const float* b2  = (const float*)d_in[22];
    const float* lng = (const float*)d_in[23];
    const float* lnb = (const float*)d_in[24];
    const float* cW  = (const float*)d_in[25];
    const float* cb  = (const float*)d_in[26];
    float* out = (float*)d_out;
    float* ws  = (float*)d_ws;

    float*    proj  = ws;                      // 8192
    float*    fused = ws + 8192;               // 16384
    float*    probs = ws + 24576;              // 256
    float*    pn    = ws + 33024 - 8192;       // = ws+24832, 64
    int*      sel   = (int*)(ws + 24896);      // 64
    float*    h1    = ws + 24960;              // 131072
    float*    eo    = ws + 156032;             // 65536
    unsigned* slots = (unsigned*)(ws + 221568);// 4*256 uints
    unsigned* LC    = (unsigned*)(ws + 222592);// 1 uint

    fused_all<<<NBLK, NTHR, 0, stream>>>(
        smiles, sW, sb, Wv, bv, Wo, bo, gW, gb, W1, b1, W2, b2,
        lng, lnb, cW, cb,
        proj, fused, probs, pn, sel, h1, eo, slots, LC, out);
}

// Round 4
// 152.142 us; speedup vs baseline: 1.9939x; 1.9939x over previous
//
#include <hip/hip_runtime.h>
#include <math.h>

#define HD 256
#define SD 768
#define D2 512
#define NE 8
#define NB 32
#define NBLK 256
#define NTHR 256

__device__ __forceinline__ float gelu_exact(float x) {
    return 0.5f * x * (1.0f + erff(x * 0.70710678118654752f));
}

// Init-agnostic grid barrier: per-barrier slot array, per-launch token.
// Block b publishes tok to slots[b]; thread t spins on slots[t].
// CRITICAL (R3 lesson): spin with RELAXED agent loads (no cache invalidate);
// do the acquire (L1/L2 invalidate) exactly ONCE after the spin breaks.
__device__ __forceinline__ void gsync(unsigned* slots, unsigned tok) {
    __syncthreads();
    __builtin_amdgcn_fence(__ATOMIC_RELEASE, "agent");   // write-back once
    if (threadIdx.x == 0)
        __hip_atomic_store(slots + blockIdx.x, tok, __ATOMIC_RELAXED,
                           __HIP_MEMORY_SCOPE_AGENT);
    for (;;) {
        unsigned v = __hip_atomic_load(slots + threadIdx.x, __ATOMIC_RELAXED,
                                       __HIP_MEMORY_SCOPE_AGENT);
        if (v == tok) break;
        __builtin_amdgcn_s_sleep(8);
    }
    __builtin_amdgcn_fence(__ATOMIC_ACQUIRE, "agent");   // invalidate once
    __syncthreads();
}

// Shared-memory carve-up (floats): big staging buffer + W tile + reduce + small
#define S_BIG   0        // 32*520 = 16640  (E1/E2 staging; P0 s_in; P1 s_p/s_v/s_f2)
#define S_W     16640    // 128*16 = 2048
#define S_RED   18688    // 256
#define S_SMALL 18944    // 16
#define SMEM_F  18960    // 75,840 B -> 2 blocks/CU capacity

__global__ __launch_bounds__(256) void fused_all(
    const float* __restrict__ smiles,
    const float* __restrict__ sW, const float* __restrict__ sb,
    const float* __restrict__ Wv, const float* __restrict__ bv,
    const float* __restrict__ Wo, const float* __restrict__ bo,
    const float* __restrict__ gW, const float* __restrict__ gb,
    const float* __restrict__ W1, const float* __restrict__ b1,
    const float* __restrict__ W2, const float* __restrict__ b2,
    const float* __restrict__ lng, const float* __restrict__ lnb,
    const float* __restrict__ clsW, const float* __restrict__ clsb,
    float* __restrict__ proj, float* __restrict__ fused,
    float* __restrict__ probs, float* __restrict__ pn,
    int* __restrict__ sel, float* __restrict__ h1,
    float* __restrict__ eo, unsigned* __restrict__ slots,
    unsigned* __restrict__ LC, float* __restrict__ out)
{
    __shared__ __align__(16) float smem[SMEM_F];
    __shared__ unsigned s_lc;
    const int bid = blockIdx.x, t = threadIdx.x;

    if (t == 0)
        s_lc = __hip_atomic_load(LC, __ATOMIC_ACQUIRE, __HIP_MEMORY_SCOPE_AGENT);
    __syncthreads();
    const unsigned tb = s_lc * 2654435761u;

    // ---------------- P0: proj = smiles @ sW + sb (256 blocks) ----------------
    {
        int r = bid >> 3, sl = bid & 7;
        float* s_in = smem + S_BIG;                 // 768
        float* s_red = smem + S_RED;
        const float* srow = smiles + (size_t)r * SD;
        for (int i = t; i < SD / 4; i += NTHR)
            ((float4*)s_in)[i] = ((const float4*)srow)[i];
        __syncthreads();
        int c = t & 31, kq = t >> 5;                // 32 cols x 8 k-quadrants
        float acc = 0.f;
        const float* wp = sW + (size_t)(kq * 96) * HD + sl * 32 + c;
        #pragma unroll 8
        for (int k = 0; k < 96; ++k)
            acc = fmaf(s_in[kq * 96 + k], wp[(size_t)k * HD], acc);
        s_red[t] = acc;
        __syncthreads();
        if (t < 32) {
            float s = 0.f;
            #pragma unroll
            for (int q = 0; q < 8; ++q) s += s_red[q * 32 + t];
            int col = sl * 32 + t;
            s += sb[col];
            proj[r * HD + col] = s;
            fused[(size_t)r * 2 * HD + HD + col] = s;   // second half = proj
        }
    }
    gsync(slots + 0 * NBLK, tb + 1u);

    // ---------------- P1: v -> attended -> gate/top2 (32 blocks) --------------
    if (bid < NB) {
        int b = bid;
        float* s_p  = smem + S_BIG;          // 256
        float* s_v  = smem + S_BIG + 256;    // 256
        float* s_f2 = smem + S_BIG + 512;    // 512
        float* s_red = smem + S_RED;
        float* s_gate = smem + S_SMALL;
        for (int i = t; i < HD; i += NTHR) s_p[i] = proj[b * HD + i];
        __syncthreads();
        float vv = bv[t];
        #pragma unroll 16
        for (int k = 0; k < HD; ++k) vv = fmaf(s_p[k], Wv[(size_t)k * HD + t], vv);
        s_v[t] = vv;
        __syncthreads();
        float att = bo[t];
        #pragma unroll 16
        for (int k = 0; k < HD; ++k) att = fmaf(s_v[k], Wo[(size_t)k * HD + t], att);
        s_f2[t] = att;
        s_f2[HD + t] = s_p[t];
        fused[(size_t)b * 2 * HD + t] = att;
        __syncthreads();

        int e = t & 7, ch = t >> 3;
        float gp = 0.f;
        #pragma unroll
        for (int j = 0; j < 16; ++j) {
            int d = ch * 16 + j;
            gp = fmaf(s_f2[d], gW[d * NE + e], gp);
        }
        s_red[t] = gp;
        __syncthreads();
        for (int off = 128; off >= 8; off >>= 1) {
            if (t < off) s_red[t] += s_red[t + off];
            __syncthreads();
        }
        if (t < NE) s_gate[t] = s_red[t] + gb[t];
        __syncthreads();
        if (t == 0) {
            float m = s_gate[0];
            for (int i = 1; i < NE; ++i) m = fmaxf(m, s_gate[i]);
            float ex[NE], ssum = 0.f;
            for (int i = 0; i < NE; ++i) { ex[i] = expf(s_gate[i] - m); ssum += ex[i]; }
            float pr[NE];
            for (int i = 0; i < NE; ++i) { pr[i] = ex[i] / ssum; probs[b * NE + i] = pr[i]; }
            int i1 = 0;
            for (int i = 1; i < NE; ++i) if (pr[i] > pr[i1]) i1 = i;
            int i2 = (i1 == 0) ? 1 : 0;
            for (int i = 0; i < NE; ++i) if (i != i1 && pr[i] > pr[i2]) i2 = i;
            float p1 = pr[i1], p2 = pr[i2], s12 = p1 + p2;
            sel[b * 2 + 0] = i1;
            sel[b * 2 + 1] = i2;
            pn[b * 2 + 0] = p1 / s12;
            pn[b * 2 + 1] = p2 / s12;
        }
    }
    gsync(slots + 1 * NBLK, tb + 2u);

    // ---------------- P2: h1 = gelu(fused @ W1[e] + b1[e]) (256 blocks) -------
    {
        int e = bid >> 5, ct = bid & 31;
        float* s_f = smem + S_BIG;    // [32][520]
        float* s_w = smem + S_W;      // [128][16]
        for (int i = t; i < NB * D2 / 4; i += NTHR) {
            int row = i >> 7, f = i & 127;
            *(float4*)&s_f[row * 520 + f * 4] = ((const float4*)fused)[i];
        }
        int c = t & 15, rg = t >> 4, r0 = rg * 2, r1 = r0 + 1;
        float a0 = 0.f, a1 = 0.f, a2 = 0.f, a3 = 0.f;
        const float* W = W1 + (size_t)e * D2 * D2 + ct * 16;
        for (int k0 = 0; k0 < D2; k0 += 128) {
            __syncthreads();
            for (int i = t; i < 128 * 4; i += NTHR) {
                int kk = i >> 2, f = i & 3;
                *(float4*)&s_w[kk * 16 + f * 4] =
                    *(const float4*)(W + (size_t)(k0 + kk) * D2 + f * 4);
            }
            __syncthreads();
            #pragma unroll 8
            for (int kk = 0; kk < 128; kk += 2) {
                float w0 = s_w[kk * 16 + c], w1 = s_w[(kk + 1) * 16 + c];
                a0 = fmaf(s_f[r0 * 520 + k0 + kk], w0, a0);
                a1 = fmaf(s_f[r0 * 520 + k0 + kk + 1], w1, a1);
                a2 = fmaf(s_f[r1 * 520 + k0 + kk], w0, a2);
                a3 = fmaf(s_f[r1 * 520 + k0 + kk + 1], w1, a3);
            }
        }
        int col = ct * 16 + c;
        float bias = b1[e * D2 + col];
        h1[((size_t)e * NB + r0) * D2 + col] = gelu_exact(a0 + a1 + bias);
        h1[((size_t)e * NB + r1) * D2 + col] = gelu_exact(a2 + a3 + bias);
    }
    gsync(slots + 2 * NBLK, tb + 3u);

    // ---------------- P3: eo = h1 @ W2[e] + b2[e] (128 blocks) ----------------
    if (bid < 128) {
        int e = bid >> 4, ct = bid & 15;
        float* s_h = smem + S_BIG;
        float* s_w = smem + S_W;
        const float4* src = (const float4*)(h1 + (size_t)e * NB * D2);
        for (int i = t; i < NB * D2 / 4; i += NTHR) {
            int row = i >> 7, f = i & 127;
            *(float4*)&s_h[row * 520 + f * 4] = src[i];
        }
        int c = t & 15, rg = t >> 4, r0 = rg * 2, r1 = r0 + 1;
        float a0 = 0.f, a1 = 0.f, a2 = 0.f, a3 = 0.f;
        const float* W = W2 + (size_t)e * D2 * HD + ct * 16;
        for (int k0 = 0; k0 < D2; k0 += 128) {
            __syncthreads();
            for (int i = t; i < 128 * 4; i += NTHR) {
                int kk = i >> 2, f = i & 3;
                *(float4*)&s_w[kk * 16 + f * 4] =
                    *(const float4*)(W + (size_t)(k0 + kk) * HD + f * 4);
            }
            __syncthreads();
            #pragma unroll 8
            for (int kk = 0; kk < 128; kk += 2) {
                float w0 = s_w[kk * 16 + c], w1 = s_w[(kk + 1) * 16 + c];
                a0 = fmaf(s_h[r0 * 520 + k0 + kk], w0, a0);
                a1 = fmaf(s_h[r0 * 520 + k0 + kk + 1], w1, a1);
                a2 = fmaf(s_h[r1 * 520 + k0 + kk], w0, a2);
                a3 = fmaf(s_h[r1 * 520 + k0 + kk + 1], w1, a3);
            }
        }
        int col = ct * 16 + c;
        float bias = b2[e * HD + col];
        eo[((size_t)e * NB + r0) * HD + col] = a0 + a1 + bias;
        eo[((size_t)e * NB + r1) * HD + col] = a2 + a3 + bias;
    }
    gsync(slots + 3 * NBLK, tb + 4u);

    // launch-token bump: safe — every block already read LC before barrier 1
    if (bid == 0 && t == 0)
        __hip_atomic_store(LC, s_lc + 1u, __ATOMIC_RELEASE, __HIP_MEMORY_SCOPE_AGENT);

    // ---------------- P4: gather/combine, LN, classifier, aux (32 blocks) -----
    if (bid < NB) {
        int b = bid;
        float* s_red = smem + S_RED;
        float* s_stats = smem + S_SMALL;
        int e0 = sel[b * 2 + 0], e1 = sel[b * 2 + 1];
        float p0 = pn[b * 2 + 0], p1 = pn[b * 2 + 1];
        float moe = p0 * eo[((size_t)e0 * NB + b) * HD + t]
                  + p1 * eo[((size_t)e1 * NB + b) * HD + t];

        s_red[t] = moe; __syncthreads();
        for (int off = 128; off > 0; off >>= 1) {
            if (t < off) s_red[t] += s_red[t + off];
            __syncthreads();
        }
        if (t == 0) s_stats[0] = s_red[0] * (1.f / HD);
        __syncthreads();
        float mu = s_stats[0];
        float d = moe - mu;

        s_red[t] = d * d; __syncthreads();
        for (int off = 128; off > 0; off >>= 1) {
            if (t < off) s_red[t] += s_red[t + off];
            __syncthreads();
        }
        if (t == 0) s_stats[1] = s_red[0] * (1.f / HD);
        __syncthreads();

        float xn = d * rsqrtf(s_stats[1] + 1e-5f);
        float y = fmaf(xn, lng[t], lnb[t]);

        s_red[t] = y * clsW[t * 2 + 0]; __syncthreads();
        for (int off = 128; off > 0; off >>= 1) {
            if (t < off) s_red[t] += s_red[t + off];
            __syncthreads();
        }
        if (t == 0) s_stats[2] = s_red[0] + clsb[0];
        __syncthreads();

        s_red[t] = y * clsW[t * 2 + 1]; __syncthreads();
        for (int off = 128; off > 0; off >>= 1) {
            if (t < off) s_red[t] += s_red[t + off];
            __syncthreads();
        }
        if (t == 0) {
            out[b * 2 + 0] = s_stats[2];
            out[b * 2 + 1] = s_red[0] + clsb[1];
        }

        if (bid == 0) {
            __syncthreads();
            s_red[t] = probs[t];
            __syncthreads();
            for (int off = 128; off >= 8; off >>= 1) {
                if (t < off) s_red[t] += s_red[t + off];
                __syncthreads();
            }
            if (t == 0) {
                float aux = 0.f;
                for (int e = 0; e < NE; ++e) {
                    float u = s_red[e] * (1.f / 32.f);
                    aux += u * logf(0.125f) - logf(u) * 0.125f;
                }
                out[64] = 0.1f * aux;
            }
        }
    }
}

extern "C" void kernel_launch(void* const* d_in, const int* in_sizes, int n_in,
                              void* d_out, int out_size, void* d_ws, size_t ws_size,
                              hipStream_t stream) {
    (void)in_sizes; (void)n_in; (void)out_size; (void)ws_size;
    const float* smiles = (const float*)d_in[2];
    const float* sW  = (const float*)d_in[7];
    const float* sb  = (const float*)d_in[8];
    const float* Wv  = (const float*)d_in[13];
    const float* bv  = (const float*)d_in[14];
    const float* Wo  = (const float*)d_in[15];
    const float* bo  = (const float*)d_in[16];
    const float* gW  = (const float*)d_in[17];
    const float* gb  = (const float*)d_in[18];
    const float* W1  = (const float*)d_in[19];
    const float* b1  = (const float*)d_in[20];
    const float* W2  = (const float*)d_in[21];
    const float* b2  = (const float*)d_in[22];
    const float* lng = (const float*)d_in[23];
    const float* lnb = (const float*)d_in[24];
    const float* cW  = (const float*)d_in[25];
    const float* cb  = (const float*)d_in[26];
    float* out = (float*)d_out;
    float* ws  = (float*)d_ws;

    float*    proj  = ws;                      // 8192
    float*    fused = ws + 8192;               // 16384
    float*    probs = ws + 24576;              // 256
    float*    pn    = ws + 24832;              // 64
    int*      sel   = (int*)(ws + 24896);      // 64
    float*    h1    = ws + 24960;              // 131072
    float*    eo    = ws + 156032;             // 65536
    unsigned* slots = (unsigned*)(ws + 221568);// 4*256 uints
    unsigned* LC    = (unsigned*)(ws + 222592);// 1 uint

    fused_all<<<NBLK, NTHR, 0, stream>>>(
        smiles, sW, sb, Wv, bv, Wo, bo, gW, gb, W1, b1, W2, b2,
        lng, lnb, cW, cb,
        proj, fused, probs, pn, sel, h1, eo, slots, LC, out);
}

// Round 5
// 95.177 us; speedup vs baseline: 3.1872x; 1.5985x over previous
//
#include <hip/hip_runtime.h>
#include <math.h>

#define HD 256
#define SD 768
#define D2 512
#define NE 8
#define NB 32
#define NBLK 256
#define NTHR 256

__device__ __forceinline__ float gelu_exact(float x) {
    return 0.5f * x * (1.0f + erff(x * 0.70710678118654752f));
}

// ---- Coherent (L2-bypassing) access for cross-block intermediates ----------
// Relaxed agent-scope atomics lower to global_load/store with sc1: they hit
// the L3/Infinity-Cache coherence point directly. NO cache-maintenance ops.
__device__ __forceinline__ void cstf(float* p, float v) {
    __hip_atomic_store(p, v, __ATOMIC_RELAXED, __HIP_MEMORY_SCOPE_AGENT);
}
__device__ __forceinline__ float cldf(const float* p) {
    return __hip_atomic_load(p, __ATOMIC_RELAXED, __HIP_MEMORY_SCOPE_AGENT);
}
__device__ __forceinline__ void csti(int* p, int v) {
    __hip_atomic_store(p, v, __ATOMIC_RELAXED, __HIP_MEMORY_SCOPE_AGENT);
}
__device__ __forceinline__ int cldi(const int* p) {
    return __hip_atomic_load(p, __ATOMIC_RELAXED, __HIP_MEMORY_SCOPE_AGENT);
}

// Init-agnostic grid barrier. R4 lesson: NO agent-scope fences anywhere —
// they force L2 writeback/invalidate on non-coherent XCDs (~140us/launch).
// __syncthreads() already drains each wave's vmem (compiler emits
// s_waitcnt vmcnt(0) before s_barrier), so sc1 data stores are complete at
// the coherence point before the flag store issues. Workgroup fences are
// waitcnt-only (no cache ops) and just pin compiler ordering.
__device__ __forceinline__ void gsync(unsigned* slots, unsigned tok) {
    __syncthreads();
    __builtin_amdgcn_fence(__ATOMIC_RELEASE, "workgroup");
    if (threadIdx.x == 0)
        __hip_atomic_store(slots + blockIdx.x, tok, __ATOMIC_RELAXED,
                           __HIP_MEMORY_SCOPE_AGENT);
    for (;;) {
        unsigned v = __hip_atomic_load(slots + threadIdx.x, __ATOMIC_RELAXED,
                                       __HIP_MEMORY_SCOPE_AGENT);
        if (v == tok) break;
        __builtin_amdgcn_s_sleep(2);
    }
    __builtin_amdgcn_fence(__ATOMIC_ACQUIRE, "workgroup");
    __syncthreads();
}

// Shared-memory carve-up (floats)
#define S_BIG   0        // 32*520 = 16640
#define S_W     16640    // 128*16 = 2048
#define S_RED   18688    // 256
#define S_SMALL 18944    // 16
#define SMEM_F  18960    // 75,840 B -> all 256 blocks co-resident on 256 CUs

__global__ __launch_bounds__(256) void fused_all(
    const float* __restrict__ smiles,
    const float* __restrict__ sW, const float* __restrict__ sb,
    const float* __restrict__ Wv, const float* __restrict__ bv,
    const float* __restrict__ Wo, const float* __restrict__ bo,
    const float* __restrict__ gW, const float* __restrict__ gb,
    const float* __restrict__ W1, const float* __restrict__ b1,
    const float* __restrict__ W2, const float* __restrict__ b2,
    const float* __restrict__ lng, const float* __restrict__ lnb,
    const float* __restrict__ clsW, const float* __restrict__ clsb,
    float* __restrict__ proj, float* __restrict__ fused,
    float* __restrict__ probs, float* __restrict__ pn,
    int* __restrict__ sel, float* __restrict__ h1,
    float* __restrict__ eo, unsigned* __restrict__ slots,
    unsigned* __restrict__ LC, float* __restrict__ out)
{
    __shared__ __align__(16) float smem[SMEM_F];
    __shared__ unsigned s_lc;
    const int bid = blockIdx.x, t = threadIdx.x;

    if (t == 0)
        s_lc = __hip_atomic_load(LC, __ATOMIC_RELAXED, __HIP_MEMORY_SCOPE_AGENT);
    __syncthreads();
    const unsigned tb = s_lc * 2654435761u;

    // ---------------- P0: proj = smiles @ sW + sb (256 blocks) ----------------
    {
        int r = bid >> 3, sl = bid & 7;
        float* s_in = smem + S_BIG;                 // 768
        float* s_red = smem + S_RED;
        const float* srow = smiles + (size_t)r * SD;
        for (int i = t; i < SD / 4; i += NTHR)
            ((float4*)s_in)[i] = ((const float4*)srow)[i];
        __syncthreads();
        int c = t & 31, kq = t >> 5;                // 32 cols x 8 k-quadrants
        float acc = 0.f;
        const float* wp = sW + (size_t)(kq * 96) * HD + sl * 32 + c;
        #pragma unroll 8
        for (int k = 0; k < 96; ++k)
            acc = fmaf(s_in[kq * 96 + k], wp[(size_t)k * HD], acc);
        s_red[t] = acc;
        __syncthreads();
        if (t < 32) {
            float s = 0.f;
            #pragma unroll
            for (int q = 0; q < 8; ++q) s += s_red[q * 32 + t];
            int col = sl * 32 + t;
            s += sb[col];
            cstf(proj + r * HD + col, s);
            cstf(fused + (size_t)r * 2 * HD + HD + col, s);   // 2nd half = proj
        }
    }
    gsync(slots + 0 * NBLK, tb + 1u);

    // ---------------- P1: v -> attended -> gate/top2 (32 blocks) --------------
    if (bid < NB) {
        int b = bid;
        float* s_p  = smem + S_BIG;          // 256
        float* s_v  = smem + S_BIG + 256;    // 256
        float* s_f2 = smem + S_BIG + 512;    // 512
        float* s_red = smem + S_RED;
        float* s_gate = smem + S_SMALL;
        s_p[t] = cldf(proj + b * HD + t);
        __syncthreads();
        float vv = bv[t];
        #pragma unroll 16
        for (int k = 0; k < HD; ++k) vv = fmaf(s_p[k], Wv[(size_t)k * HD + t], vv);
        s_v[t] = vv;
        __syncthreads();
        float att = bo[t];
        #pragma unroll 16
        for (int k = 0; k < HD; ++k) att = fmaf(s_v[k], Wo[(size_t)k * HD + t], att);
        s_f2[t] = att;
        s_f2[HD + t] = s_p[t];
        cstf(fused + (size_t)b * 2 * HD + t, att);
        __syncthreads();

        int e = t & 7, ch = t >> 3;
        float gp = 0.f;
        #pragma unroll
        for (int j = 0; j < 16; ++j) {
            int d = ch * 16 + j;
            gp = fmaf(s_f2[d], gW[d * NE + e], gp);
        }
        s_red[t] = gp;
        __syncthreads();
        for (int off = 128; off >= 8; off >>= 1) {
            if (t < off) s_red[t] += s_red[t + off];
            __syncthreads();
        }
        if (t < NE) s_gate[t] = s_red[t] + gb[t];
        __syncthreads();
        if (t == 0) {
            float m = s_gate[0];
            for (int i = 1; i < NE; ++i) m = fmaxf(m, s_gate[i]);
            float ex[NE], ssum = 0.f;
            for (int i = 0; i < NE; ++i) { ex[i] = expf(s_gate[i] - m); ssum += ex[i]; }
            float pr[NE];
            for (int i = 0; i < NE; ++i) { pr[i] = ex[i] / ssum; cstf(probs + b * NE + i, pr[i]); }
            int i1 = 0;
            for (int i = 1; i < NE; ++i) if (pr[i] > pr[i1]) i1 = i;
            int i2 = (i1 == 0) ? 1 : 0;
            for (int i = 0; i < NE; ++i) if (i != i1 && pr[i] > pr[i2]) i2 = i;
            float p1 = pr[i1], p2 = pr[i2], s12 = p1 + p2;
            csti(sel + b * 2 + 0, i1);
            csti(sel + b * 2 + 1, i2);
            cstf(pn + b * 2 + 0, p1 / s12);
            cstf(pn + b * 2 + 1, p2 / s12);
        }
    }
    gsync(slots + 1 * NBLK, tb + 2u);

    // ---------------- P2: h1 = gelu(fused @ W1[e] + b1[e]) (256 blocks) -------
    {
        int e = bid >> 5, ct = bid & 31;
        float* s_f = smem + S_BIG;    // [32][520]
        float* s_w = smem + S_W;      // [128][16]
        for (int i = t; i < NB * D2; i += NTHR) {
            int row = i >> 9, f = i & 511;
            s_f[row * 520 + f] = cldf(fused + i);
        }
        int c = t & 15, rg = t >> 4, r0 = rg * 2, r1 = r0 + 1;
        float a0 = 0.f, a1 = 0.f, a2 = 0.f, a3 = 0.f;
        const float* W = W1 + (size_t)e * D2 * D2 + ct * 16;
        for (int k0 = 0; k0 < D2; k0 += 128) {
            __syncthreads();
            for (int i = t; i < 128 * 4; i += NTHR) {
                int kk = i >> 2, f = i & 3;
                *(float4*)&s_w[kk * 16 + f * 4] =
                    *(const float4*)(W + (size_t)(k0 + kk) * D2 + f * 4);
            }
            __syncthreads();
            #pragma unroll 8
            for (int kk = 0; kk < 128; kk += 2) {
                float w0 = s_w[kk * 16 + c], w1 = s_w[(kk + 1) * 16 + c];
                a0 = fmaf(s_f[r0 * 520 + k0 + kk], w0, a0);
                a1 = fmaf(s_f[r0 * 520 + k0 + kk + 1], w1, a1);
                a2 = fmaf(s_f[r1 * 520 + k0 + kk], w0, a2);
                a3 = fmaf(s_f[r1 * 520 + k0 + kk + 1], w1, a3);
            }
        }
        int col = ct * 16 + c;
        float bias = b1[e * D2 + col];
        cstf(h1 + ((size_t)e * NB + r0) * D2 + col, gelu_exact(a0 + a1 + bias));
        cstf(h1 + ((size_t)e * NB + r1) * D2 + col, gelu_exact(a2 + a3 + bias));
    }
    gsync(slots + 2 * NBLK, tb + 3u);

    // ---------------- P3: eo = h1 @ W2[e] + b2[e] (128 blocks) ----------------
    if (bid < 128) {
        int e = bid >> 4, ct = bid & 15;
        float* s_h = smem + S_BIG;
        float* s_w = smem + S_W;
        const float* src = h1 + (size_t)e * NB * D2;
        for (int i = t; i < NB * D2; i += NTHR) {
            int row = i >> 9, f = i & 511;
            s_h[row * 520 + f] = cldf(src + i);
        }
        int c = t & 15, rg = t >> 4, r0 = rg * 2, r1 = r0 + 1;
        float a0 = 0.f, a1 = 0.f, a2 = 0.f, a3 = 0.f;
        const float* W = W2 + (size_t)e * D2 * HD + ct * 16;
        for (int k0 = 0; k0 < D2; k0 += 128) {
            __syncthreads();
            for (int i = t; i < 128 * 4; i += NTHR) {
                int kk = i >> 2, f = i & 3;
                *(float4*)&s_w[kk * 16 + f * 4] =
                    *(const float4*)(W + (size_t)(k0 + kk) * HD + f * 4);
            }
            __syncthreads();
            #pragma unroll 8
            for (int kk = 0; kk < 128; kk += 2) {
                float w0 = s_w[kk * 16 + c], w1 = s_w[(kk + 1) * 16 + c];
                a0 = fmaf(s_h[r0 * 520 + k0 + kk], w0, a0);
                a1 = fmaf(s_h[r0 * 520 + k0 + kk + 1], w1, a1);
                a2 = fmaf(s_h[r1 * 520 + k0 + kk], w0, a2);
                a3 = fmaf(s_h[r1 * 520 + k0 + kk + 1], w1, a3);
            }
        }
        int col = ct * 16 + c;
        float bias = b2[e * HD + col];
        cstf(eo + ((size_t)e * NB + r0) * HD + col, a0 + a1 + bias);
        cstf(eo + ((size_t)e * NB + r1) * HD + col, a2 + a3 + bias);
    }
    gsync(slots + 3 * NBLK, tb + 4u);

    // launch-token bump: safe — every block already read LC before barrier 1
    if (bid == 0 && t == 0)
        __hip_atomic_store(LC, s_lc + 1u, __ATOMIC_RELAXED, __HIP_MEMORY_SCOPE_AGENT);

    // ---------------- P4: gather/combine, LN, classifier, aux (32 blocks) -----
    if (bid < NB) {
        int b = bid;
        float* s_red = smem + S_RED;
        float* s_stats = smem + S_SMALL;
        int e0 = cldi(sel + b * 2 + 0), e1 = cldi(sel + b * 2 + 1);
        float p0 = cldf(pn + b * 2 + 0), p1 = cldf(pn + b * 2 + 1);
        float moe = p0 * cldf(eo + ((size_t)e0 * NB + b) * HD + t)
                  + p1 * cldf(eo + ((size_t)e1 * NB + b) * HD + t);

        s_red[t] = moe; __syncthreads();
        for (int off = 128; off > 0; off >>= 1) {
            if (t < off) s_red[t] += s_red[t + off];
            __syncthreads();
        }
        if (t == 0) s_stats[0] = s_red[0] * (1.f / HD);
        __syncthreads();
        float mu = s_stats[0];
        float d = moe - mu;

        s_red[t] = d * d; __syncthreads();
        for (int off = 128; off > 0; off >>= 1) {
            if (t < off) s_red[t] += s_red[t + off];
            __syncthreads();
        }
        if (t == 0) s_stats[1] = s_red[0] * (1.f / HD);
        __syncthreads();

        float xn = d * rsqrtf(s_stats[1] + 1e-5f);
        float y = fmaf(xn, lng[t], lnb[t]);

        s_red[t] = y * clsW[t * 2 + 0]; __syncthreads();
        for (int off = 128; off > 0; off >>= 1) {
            if (t < off) s_red[t] += s_red[t + off];
            __syncthreads();
        }
        if (t == 0) s_stats[2] = s_red[0] + clsb[0];
        __syncthreads();

        s_red[t] = y * clsW[t * 2 + 1]; __syncthreads();
        for (int off = 128; off > 0; off >>= 1) {
            if (t < off) s_red[t] += s_red[t + off];
            __syncthreads();
        }
        if (t == 0) {
            out[b * 2 + 0] = s_stats[2];
            out[b * 2 + 1] = s_red[0] + clsb[1];
        }

        if (bid == 0) {
            __syncthreads();
            s_red[t] = cldf(probs + t);
            __syncthreads();
            for (int off = 128; off >= 8; off >>= 1) {
                if (t < off) s_red[t] += s_red[t + off];
                __syncthreads();
            }
            if (t == 0) {
                float aux = 0.f;
                for (int e = 0; e < NE; ++e) {
                    float u = s_red[e] * (1.f / 32.f);
                    aux += u * logf(0.125f) - logf(u) * 0.125f;
                }
                out[64] = 0.1f * aux;
            }
        }
    }
}

extern "C" void kernel_launch(void* const* d_in, const int* in_sizes, int n_in,
                              void* d_out, int out_size, void* d_ws, size_t ws_size,
                              hipStream_t stream) {
    (void)in_sizes; (void)n_in; (void)out_size; (void)ws_size;
    const float* smiles = (const float*)d_in[2];
    const float* sW  = (const float*)d_in[7];
    const float* sb  = (const float*)d_in[8];
    const float* Wv  = (const float*)d_in[13];
    const float* bv  = (const float*)d_in[14];
    const float* Wo  = (const float*)d_in[15];
    const float* bo  = (const float*)d_in[16];
    const float* gW  = (const float*)d_in[17];
    const float* gb  = (const float*)d_in[18];
    const float* W1  = (const float*)d_in[19];
    const float* b1  = (const float*)d_in[20];
    const float* W2  = (const float*)d_in[21];
    const float* b2  = (const float*)d_in[22];
    const float* lng = (const float*)d_in[23];
    const float* lnb = (const float*)d_in[24];
    const float* cW  = (const float*)d_in[25];
    const float* cb  = (const float*)d_in[26];
    float* out = (float*)d_out;
    float* ws  = (float*)d_ws;

    float*    proj  = ws;                      // 8192
    float*    fused = ws + 8192;               // 16384
    float*    probs = ws + 24576;              // 256
    float*    pn    = ws + 24832;              // 64
    int*      sel   = (int*)(ws + 24896);      // 64
    float*    h1    = ws + 24960;              // 131072
    float*    eo    = ws + 156032;             // 65536
    unsigned* slots = (unsigned*)(ws + 221568);// 4*256 uints
    unsigned* LC    = (unsigned*)(ws + 222592);// 1 uint

    fused_all<<<NBLK, NTHR, 0, stream>>>(
        smiles, sW, sb, Wv, bv, Wo, bo, gW, gb, W1, b1, W2, b2,
        lng, lnb, cW, cb,
        proj, fused, probs, pn, sel, h1, eo, slots, LC, out);
}

// Round 6
// 70.223 us; speedup vs baseline: 4.3198x; 1.3554x over previous
//
#include <hip/hip_runtime.h>
#include <math.h>

#define HD 256
#define SD 768
#define D2 512
#define NE 8
#define NB 32
#define NBLK 256
#define NTHR 256

typedef float f32x4 __attribute__((ext_vector_type(4)));

__device__ __forceinline__ float gelu_exact(float x) {
    return 0.5f * x * (1.0f + erff(x * 0.70710678118654752f));
}

// ---- Coherent (L2-bypassing) access for cross-block intermediates ----------
__device__ __forceinline__ void cstf(float* p, float v) {
    __hip_atomic_store(p, v, __ATOMIC_RELAXED, __HIP_MEMORY_SCOPE_AGENT);
}
__device__ __forceinline__ float cldf(const float* p) {
    return __hip_atomic_load(p, __ATOMIC_RELAXED, __HIP_MEMORY_SCOPE_AGENT);
}
__device__ __forceinline__ void csti(int* p, int v) {
    __hip_atomic_store(p, v, __ATOMIC_RELAXED, __HIP_MEMORY_SCOPE_AGENT);
}
__device__ __forceinline__ int cldi(const int* p) {
    return __hip_atomic_load(p, __ATOMIC_RELAXED, __HIP_MEMORY_SCOPE_AGENT);
}

// R5 lesson: scalar relaxed-atomic staging loads serialize (~700cy each, no
// pipelining). Bulk-stage 16KB global->LDS with 16 deep-pipelined coherent
// dwordx4 loads per thread (sc0 sc1 = read the L3 coherence point, skip the
// stale per-XCD L2), ONE vmcnt drain, then LDS float4 writes.
// sched_barrier(0) after the waitcnt per guide rule #18.
// LDS layout: row-major [32][520] (8-float pad), dst float-index for float4
// q (q = t + j*256): row = q>>7, col4 = (q&127)*4.
__device__ __forceinline__ void stage16k(const float* __restrict__ gsrc,
                                         float* __restrict__ lds, int t)
{
    const f32x4* src = (const f32x4*)gsrc;
    f32x4 r[16];
    #pragma unroll
    for (int j = 0; j < 16; ++j) {
        const f32x4* p = src + (t + j * 256);
        asm volatile("global_load_dwordx4 %0, %1, off sc0 sc1"
                     : "=v"(r[j]) : "v"(p));
    }
    asm volatile("s_waitcnt vmcnt(0)" ::: "memory");
    __builtin_amdgcn_sched_barrier(0);
    #pragma unroll
    for (int j = 0; j < 16; ++j) {
        int q = t + j * 256;
        *(f32x4*)&lds[(q >> 7) * 520 + (q & 127) * 4] = r[j];
    }
}

// Init-agnostic grid barrier. NO agent-scope fences (R4 lesson: they force
// L2 writeback/invalidate per wave). Workgroup fences are waitcnt-only.
__device__ __forceinline__ void gsync(unsigned* slots, unsigned tok) {
    __syncthreads();
    __builtin_amdgcn_fence(__ATOMIC_RELEASE, "workgroup");
    if (threadIdx.x == 0)
        __hip_atomic_store(slots + blockIdx.x, tok, __ATOMIC_RELAXED,
                           __HIP_MEMORY_SCOPE_AGENT);
    for (;;) {
        unsigned v = __hip_atomic_load(slots + threadIdx.x, __ATOMIC_RELAXED,
                                       __HIP_MEMORY_SCOPE_AGENT);
        if (v == tok) break;
        __builtin_amdgcn_s_sleep(2);
    }
    __builtin_amdgcn_fence(__ATOMIC_ACQUIRE, "workgroup");
    __syncthreads();
}

// Shared-memory carve-up (floats)
#define S_BIG   0        // 32*520 = 16640
#define S_W     16640    // 128*16 = 2048
#define S_RED   18688    // 256
#define S_SMALL 18944    // 16
#define SMEM_F  18960    // 75,840 B

__global__ __launch_bounds__(256) void fused_all(
    const float* __restrict__ smiles,
    const float* __restrict__ sW, const float* __restrict__ sb,
    const float* __restrict__ Wv, const float* __restrict__ bv,
    const float* __restrict__ Wo, const float* __restrict__ bo,
    const float* __restrict__ gW, const float* __restrict__ gb,
    const float* __restrict__ W1, const float* __restrict__ b1,
    const float* __restrict__ W2, const float* __restrict__ b2,
    const float* __restrict__ lng, const float* __restrict__ lnb,
    const float* __restrict__ clsW, const float* __restrict__ clsb,
    float* __restrict__ proj, float* __restrict__ fused,
    float* __restrict__ probs, float* __restrict__ pn,
    int* __restrict__ sel, float* __restrict__ h1,
    float* __restrict__ eo, unsigned* __restrict__ slots,
    unsigned* __restrict__ LC, float* __restrict__ out)
{
    __shared__ __align__(16) float smem[SMEM_F];
    __shared__ unsigned s_lc;
    const int bid = blockIdx.x, t = threadIdx.x;

    if (t == 0)
        s_lc = __hip_atomic_load(LC, __ATOMIC_RELAXED, __HIP_MEMORY_SCOPE_AGENT);
    __syncthreads();
    const unsigned tb = s_lc * 2654435761u;

    // ---------------- P0: proj = smiles @ sW + sb (256 blocks) ----------------
    {
        int r = bid >> 3, sl = bid & 7;
        float* s_in = smem + S_BIG;                 // 768
        float* s_red = smem + S_RED;
        const float* srow = smiles + (size_t)r * SD;
        for (int i = t; i < SD / 4; i += NTHR)
            ((float4*)s_in)[i] = ((const float4*)srow)[i];
        __syncthreads();
        int c = t & 31, kq = t >> 5;                // 32 cols x 8 k-quadrants
        float acc = 0.f;
        const float* wp = sW + (size_t)(kq * 96) * HD + sl * 32 + c;
        #pragma unroll 8
        for (int k = 0; k < 96; ++k)
            acc = fmaf(s_in[kq * 96 + k], wp[(size_t)k * HD], acc);
        s_red[t] = acc;
        __syncthreads();
        if (t < 32) {
            float s = 0.f;
            #pragma unroll
            for (int q = 0; q < 8; ++q) s += s_red[q * 32 + t];
            int col = sl * 32 + t;
            s += sb[col];
            cstf(proj + r * HD + col, s);
            cstf(fused + (size_t)r * 2 * HD + HD + col, s);   // 2nd half = proj
        }
    }
    gsync(slots + 0 * NBLK, tb + 1u);

    // ---------------- P1: v -> attended -> gate/top2 (32 blocks) --------------
    if (bid < NB) {
        int b = bid;
        float* s_p  = smem + S_BIG;          // 256
        float* s_v  = smem + S_BIG + 256;    // 256
        float* s_f2 = smem + S_BIG + 512;    // 512
        float* s_red = smem + S_RED;
        float* s_gate = smem + S_SMALL;
        s_p[t] = cldf(proj + b * HD + t);
        __syncthreads();
        float vv = bv[t];
        #pragma unroll 16
        for (int k = 0; k < HD; ++k) vv = fmaf(s_p[k], Wv[(size_t)k * HD + t], vv);
        s_v[t] = vv;
        __syncthreads();
        float att = bo[t];
        #pragma unroll 16
        for (int k = 0; k < HD; ++k) att = fmaf(s_v[k], Wo[(size_t)k * HD + t], att);
        s_f2[t] = att;
        s_f2[HD + t] = s_p[t];
        cstf(fused + (size_t)b * 2 * HD + t, att);
        __syncthreads();

        int e = t & 7, ch = t >> 3;
        float gp = 0.f;
        #pragma unroll
        for (int j = 0; j < 16; ++j) {
            int d = ch * 16 + j;
            gp = fmaf(s_f2[d], gW[d * NE + e], gp);
        }
        s_red[t] = gp;
        __syncthreads();
        for (int off = 128; off >= 8; off >>= 1) {
            if (t < off) s_red[t] += s_red[t + off];
            __syncthreads();
        }
        if (t < NE) s_gate[t] = s_red[t] + gb[t];
        __syncthreads();
        if (t == 0) {
            float m = s_gate[0];
            for (int i = 1; i < NE; ++i) m = fmaxf(m, s_gate[i]);
            float ex[NE], ssum = 0.f;
            for (int i = 0; i < NE; ++i) { ex[i] = expf(s_gate[i] - m); ssum += ex[i]; }
            float pr[NE];
            for (int i = 0; i < NE; ++i) { pr[i] = ex[i] / ssum; cstf(probs + b * NE + i, pr[i]); }
            int i1 = 0;
            for (int i = 1; i < NE; ++i) if (pr[i] > pr[i1]) i1 = i;
            int i2 = (i1 == 0) ? 1 : 0;
            for (int i = 0; i < NE; ++i) if (i != i1 && pr[i] > pr[i2]) i2 = i;
            float p1 = pr[i1], p2 = pr[i2], s12 = p1 + p2;
            csti(sel + b * 2 + 0, i1);
            csti(sel + b * 2 + 1, i2);
            cstf(pn + b * 2 + 0, p1 / s12);
            cstf(pn + b * 2 + 1, p2 / s12);
        }
    }
    gsync(slots + 1 * NBLK, tb + 2u);

    // ---------------- P2: h1 = gelu(fused @ W1[e] + b1[e]) (256 blocks) -------
    {
        int e = bid >> 5, ct = bid & 31;
        float* s_f = smem + S_BIG;    // [32][520]
        float* s_w = smem + S_W;      // [128][16]
        stage16k(fused, s_f, t);
        int c = t & 15, rg = t >> 4, r0 = rg * 2, r1 = r0 + 1;
        float a0 = 0.f, a1 = 0.f, a2 = 0.f, a3 = 0.f;
        const float* W = W1 + (size_t)e * D2 * D2 + ct * 16;
        for (int k0 = 0; k0 < D2; k0 += 128) {
            __syncthreads();
            for (int i = t; i < 128 * 4; i += NTHR) {
                int kk = i >> 2, f = i & 3;
                *(float4*)&s_w[kk * 16 + f * 4] =
                    *(const float4*)(W + (size_t)(k0 + kk) * D2 + f * 4);
            }
            __syncthreads();
            #pragma unroll 8
            for (int kk = 0; kk < 128; kk += 2) {
                float w0 = s_w[kk * 16 + c], w1 = s_w[(kk + 1) * 16 + c];
                a0 = fmaf(s_f[r0 * 520 + k0 + kk], w0, a0);
                a1 = fmaf(s_f[r0 * 520 + k0 + kk + 1], w1, a1);
                a2 = fmaf(s_f[r1 * 520 + k0 + kk], w0, a2);
                a3 = fmaf(s_f[r1 * 520 + k0 + kk + 1], w1, a3);
            }
        }
        int col = ct * 16 + c;
        float bias = b1[e * D2 + col];
        cstf(h1 + ((size_t)e * NB + r0) * D2 + col, gelu_exact(a0 + a1 + bias));
        cstf(h1 + ((size_t)e * NB + r1) * D2 + col, gelu_exact(a2 + a3 + bias));
    }
    gsync(slots + 2 * NBLK, tb + 3u);

    // ---------------- P3: eo = h1 @ W2[e] + b2[e] (128 blocks) ----------------
    if (bid < 128) {
        int e = bid >> 4, ct = bid & 15;
        float* s_h = smem + S_BIG;
        float* s_w = smem + S_W;
        stage16k(h1 + (size_t)e * NB * D2, s_h, t);
        int c = t & 15, rg = t >> 4, r0 = rg * 2, r1 = r0 + 1;
        float a0 = 0.f, a1 = 0.f, a2 = 0.f, a3 = 0.f;
        const float* W = W2 + (size_t)e * D2 * HD + ct * 16;
        for (int k0 = 0; k0 < D2; k0 += 128) {
            __syncthreads();
            for (int i = t; i < 128 * 4; i += NTHR) {
                int kk = i >> 2, f = i & 3;
                *(float4*)&s_w[kk * 16 + f * 4] =
                    *(const float4*)(W + (size_t)(k0 + kk) * HD + f * 4);
            }
            __syncthreads();
            #pragma unroll 8
            for (int kk = 0; kk < 128; kk += 2) {
                float w0 = s_w[kk * 16 + c], w1 = s_w[(kk + 1) * 16 + c];
                a0 = fmaf(s_h[r0 * 520 + k0 + kk], w0, a0);
                a1 = fmaf(s_h[r0 * 520 + k0 + kk + 1], w1, a1);
                a2 = fmaf(s_h[r1 * 520 + k0 + kk], w0, a2);
                a3 = fmaf(s_h[r1 * 520 + k0 + kk + 1], w1, a3);
            }
        }
        int col = ct * 16 + c;
        float bias = b2[e * HD + col];
        cstf(eo + ((size_t)e * NB + r0) * HD + col, a0 + a1 + bias);
        cstf(eo + ((size_t)e * NB + r1) * HD + col, a2 + a3 + bias);
    }
    gsync(slots + 3 * NBLK, tb + 4u);

    // launch-token bump: safe — every block already read LC before barrier 1
    if (bid == 0 && t == 0)
        __hip_atomic_store(LC, s_lc + 1u, __ATOMIC_RELAXED, __HIP_MEMORY_SCOPE_AGENT);

    // ---------------- P4: gather/combine, LN, classifier, aux (32 blocks) -----
    if (bid < NB) {
        int b = bid;
        float* s_red = smem + S_RED;
        float* s_stats = smem + S_SMALL;
        int e0 = cldi(sel + b * 2 + 0), e1 = cldi(sel + b * 2 + 1);
        float p0 = cldf(pn + b * 2 + 0), p1 = cldf(pn + b * 2 + 1);
        float moe = p0 * cldf(eo + ((size_t)e0 * NB + b) * HD + t)
                  + p1 * cldf(eo + ((size_t)e1 * NB + b) * HD + t);

        s_red[t] = moe; __syncthreads();
        for (int off = 128; off > 0; off >>= 1) {
            if (t < off) s_red[t] += s_red[t + off];
            __syncthreads();
        }
        if (t == 0) s_stats[0] = s_red[0] * (1.f / HD);
        __syncthreads();
        float mu = s_stats[0];
        float d = moe - mu;

        s_red[t] = d * d; __syncthreads();
        for (int off = 128; off > 0; off >>= 1) {
            if (t < off) s_red[t] += s_red[t + off];
            __syncthreads();
        }
        if (t == 0) s_stats[1] = s_red[0] * (1.f / HD);
        __syncthreads();

        float xn = d * rsqrtf(s_stats[1] + 1e-5f);
        float y = fmaf(xn, lng[t], lnb[t]);

        s_red[t] = y * clsW[t * 2 + 0]; __syncthreads();
        for (int off = 128; off > 0; off >>= 1) {
            if (t < off) s_red[t] += s_red[t + off];
            __syncthreads();
        }
        if (t == 0) s_stats[2] = s_red[0] + clsb[0];
        __syncthreads();

        s_red[t] = y * clsW[t * 2 + 1]; __syncthreads();
        for (int off = 128; off > 0; off >>= 1) {
            if (t < off) s_red[t] += s_red[t + off];
            __syncthreads();
        }
        if (t == 0) {
            out[b * 2 + 0] = s_stats[2];
            out[b * 2 + 1] = s_red[0] + clsb[1];
        }

        if (bid == 0) {
            __syncthreads();
            s_red[t] = cldf(probs + t);
            __syncthreads();
            for (int off = 128; off >= 8; off >>= 1) {
                if (t < off) s_red[t] += s_red[t + off];
                __syncthreads();
            }
            if (t == 0) {
                float aux = 0.f;
                for (int e = 0; e < NE; ++e) {
                    float u = s_red[e] * (1.f / 32.f);
                    aux += u * logf(0.125f) - logf(u) * 0.125f;
                }
                out[64] = 0.1f * aux;
            }
        }
    }
}

extern "C" void kernel_launch(void* const* d_in, const int* in_sizes, int n_in,
                              void* d_out, int out_size, void* d_ws, size_t ws_size,
                              hipStream_t stream) {
    (void)in_sizes; (void)n_in; (void)out_size; (void)ws_size;
    const float* smiles = (const float*)d_in[2];
    const float* sW  = (const float*)d_in[7];
    const float* sb  = (const float*)d_in[8];
    const float* Wv  = (const float*)d_in[13];
    const float* bv  = (const float*)d_in[14];
    const float* Wo  = (const float*)d_in[15];
    const float* bo  = (const float*)d_in[16];
    const float* gW  = (const float*)d_in[17];
    const float* gb  = (const float*)d_in[18];
    const float* W1  = (const float*)d_in[19];
    const float* b1  = (const float*)d_in[20];
    const float* W2  = (const float*)d_in[21];
    const float* b2  = (const float*)d_in[22];
    const float* lng = (const float*)d_in[23];
    const float* lnb = (const float*)d_in[24];
    const float* cW  = (const float*)d_in[25];
    const float* cb  = (const float*)d_in[26];
    float* out = (float*)d_out;
    float* ws  = (float*)d_ws;

    float*    proj  = ws;                      // 8192
    float*    fused = ws + 8192;               // 16384
    float*    probs = ws + 24576;              // 256
    float*    pn    = ws + 24832;              // 64
    int*      sel   = (int*)(ws + 24896);      // 64
    float*    h1    = ws + 24960;              // 131072
    float*    eo    = ws + 156032;             // 65536
    unsigned* slots = (unsigned*)(ws + 221568);// 4*256 uints
    unsigned* LC    = (unsigned*)(ws + 222592);// 1 uint

    fused_all<<<NBLK, NTHR, 0, stream>>>(
        smiles, sW, sb, Wv, bv, Wo, bo, gW, gb, W1, b1, W2, b2,
        lng, lnb, cW, cb,
        proj, fused, probs, pn, sel, h1, eo, slots, LC, out);
}

// Round 7
// 57.698 us; speedup vs baseline: 5.2576x; 1.2171x over previous
//
#include <hip/hip_runtime.h>
#include <math.h>

#define HD 256
#define SD 768
#define D2 512
#define NE 8
#define NB 32
#define NBLK 256
#define NTHR 256

typedef float f32x4 __attribute__((ext_vector_type(4)));
typedef unsigned u32x4 __attribute__((ext_vector_type(4)));

__device__ __forceinline__ float gelu_exact(float x) {
    return 0.5f * x * (1.0f + erff(x * 0.70710678118654752f));
}

// ---- Coherent (L2-bypassing) access for cross-block intermediates ----------
__device__ __forceinline__ void cstf(float* p, float v) {
    __hip_atomic_store(p, v, __ATOMIC_RELAXED, __HIP_MEMORY_SCOPE_AGENT);
}
__device__ __forceinline__ float cldf(const float* p) {
    return __hip_atomic_load(p, __ATOMIC_RELAXED, __HIP_MEMORY_SCOPE_AGENT);
}
__device__ __forceinline__ void csti(int* p, int v) {
    __hip_atomic_store(p, v, __ATOMIC_RELAXED, __HIP_MEMORY_SCOPE_AGENT);
}
__device__ __forceinline__ int cldi(const int* p) {
    return __hip_atomic_load(p, __ATOMIC_RELAXED, __HIP_MEMORY_SCOPE_AGENT);
}

// Bulk-stage 16KB global->LDS, 16 deep-pipelined coherent dwordx4 loads,
// one vmcnt drain, then LDS float4 writes (R6, verified).
__device__ __forceinline__ void stage16k(const float* __restrict__ gsrc,
                                         float* __restrict__ lds, int t)
{
    const f32x4* src = (const f32x4*)gsrc;
    f32x4 r[16];
    #pragma unroll
    for (int j = 0; j < 16; ++j) {
        const f32x4* p = src + (t + j * 256);
        asm volatile("global_load_dwordx4 %0, %1, off sc0 sc1"
                     : "=v"(r[j]) : "v"(p));
    }
    asm volatile("s_waitcnt vmcnt(0)" ::: "memory");
    __builtin_amdgcn_sched_barrier(0);
    #pragma unroll
    for (int j = 0; j < 16; ++j) {
        int q = t + j * 256;
        *(f32x4*)&lds[(q >> 7) * 520 + (q & 127) * 4] = r[j];
    }
}

// Grid barrier v3 (R6 lesson: all-threads-poll-all-slots thundering-herds L3,
// ~10us/barrier). Hierarchical: arrivals store slots[bid]; ONLY block 0's
// wave 0 scans the 1KB slot array (1 dwordx4/lane = whole array per round);
// when complete, thread 0 publishes one `gen` word; all other blocks poll
// gen with a single scalar load per block per round. Init-agnostic tokens.
__device__ __forceinline__ void gsync(unsigned* slots, unsigned* gen,
                                      unsigned tok) {
    __syncthreads();   // drains vmcnt -> this block's sc1 stores are at L3
    const int t = threadIdx.x;
    if (t == 0)
        __hip_atomic_store(slots + blockIdx.x, tok, __ATOMIC_RELAXED,
                           __HIP_MEMORY_SCOPE_AGENT);
    if (blockIdx.x == 0) {
        if (t < 64) {
            const u32x4* p = (const u32x4*)slots + t;
            for (;;) {
                u32x4 v;
                asm volatile("global_load_dwordx4 %0, %1, off sc0 sc1\n\t"
                             "s_waitcnt vmcnt(0)"
                             : "=&v"(v) : "v"(p) : "memory");
                bool ok = (v[0] == tok) & (v[1] == tok) &
                          (v[2] == tok) & (v[3] == tok);
                if (__ballot(ok) == ~0ull) break;
                __builtin_amdgcn_s_sleep(1);
            }
            if (t == 0)
                __hip_atomic_store(gen, tok, __ATOMIC_RELAXED,
                                   __HIP_MEMORY_SCOPE_AGENT);
        }
    } else {
        if (t == 0) {
            while (__hip_atomic_load(gen, __ATOMIC_RELAXED,
                                     __HIP_MEMORY_SCOPE_AGENT) != tok)
                __builtin_amdgcn_s_sleep(1);
        }
    }
    __builtin_amdgcn_fence(__ATOMIC_ACQUIRE, "workgroup");
    __syncthreads();
}

// Shared-memory carve-up (floats)
#define S_BIG   0        // 32*520 = 16640
#define S_W     16640    // 128*16 = 2048
#define S_RED   18688    // 256
#define S_SMALL 18944    // 16
#define SMEM_F  18960    // 75,840 B

__global__ __launch_bounds__(256) void fused_all(
    const float* __restrict__ smiles,
    const float* __restrict__ sW, const float* __restrict__ sb,
    const float* __restrict__ Wv, const float* __restrict__ bv,
    const float* __restrict__ Wo, const float* __restrict__ bo,
    const float* __restrict__ gW, const float* __restrict__ gb,
    const float* __restrict__ W1, const float* __restrict__ b1,
    const float* __restrict__ W2, const float* __restrict__ b2,
    const float* __restrict__ lng, const float* __restrict__ lnb,
    const float* __restrict__ clsW, const float* __restrict__ clsb,
    float* __restrict__ proj, float* __restrict__ fused,
    float* __restrict__ probs, float* __restrict__ pn,
    int* __restrict__ sel, float* __restrict__ h1,
    float* __restrict__ eo, unsigned* __restrict__ slots,
    unsigned* __restrict__ gen, unsigned* __restrict__ LC,
    float* __restrict__ out)
{
    __shared__ __align__(16) float smem[SMEM_F];
    __shared__ unsigned s_lc;
    const int bid = blockIdx.x, t = threadIdx.x;

    if (t == 0)
        s_lc = __hip_atomic_load(LC, __ATOMIC_RELAXED, __HIP_MEMORY_SCOPE_AGENT);
    __syncthreads();
    const unsigned tb = s_lc * 2654435761u;

    // ---------------- P0: proj = smiles @ sW + sb (256 blocks) ----------------
    {
        int r = bid >> 3, sl = bid & 7;
        float* s_in = smem + S_BIG;                 // 768
        float* s_red = smem + S_RED;
        const float* srow = smiles + (size_t)r * SD;
        for (int i = t; i < SD / 4; i += NTHR)
            ((float4*)s_in)[i] = ((const float4*)srow)[i];
        __syncthreads();
        int c = t & 31, kq = t >> 5;                // 32 cols x 8 k-quadrants
        float acc = 0.f;
        const float* wp = sW + (size_t)(kq * 96) * HD + sl * 32 + c;
        #pragma unroll 8
        for (int k = 0; k < 96; ++k)
            acc = fmaf(s_in[kq * 96 + k], wp[(size_t)k * HD], acc);
        s_red[t] = acc;
        __syncthreads();
        if (t < 32) {
            float s = 0.f;
            #pragma unroll
            for (int q = 0; q < 8; ++q) s += s_red[q * 32 + t];
            int col = sl * 32 + t;
            s += sb[col];
            cstf(proj + r * HD + col, s);
            cstf(fused + (size_t)r * 2 * HD + HD + col, s);   // 2nd half = proj
        }
    }
    gsync(slots + 0 * NBLK, gen + 0, tb + 1u);

    // ---------------- P1: v -> attended -> gate/top2 (32 blocks) --------------
    if (bid < NB) {
        int b = bid;
        float* s_p  = smem + S_BIG;          // 256
        float* s_v  = smem + S_BIG + 256;    // 256
        float* s_f2 = smem + S_BIG + 512;    // 512
        float* s_red = smem + S_RED;
        float* s_gate = smem + S_SMALL;
        s_p[t] = cldf(proj + b * HD + t);
        __syncthreads();
        float vv = bv[t];
        #pragma unroll 16
        for (int k = 0; k < HD; ++k) vv = fmaf(s_p[k], Wv[(size_t)k * HD + t], vv);
        s_v[t] = vv;
        __syncthreads();
        float att = bo[t];
        #pragma unroll 16
        for (int k = 0; k < HD; ++k) att = fmaf(s_v[k], Wo[(size_t)k * HD + t], att);
        s_f2[t] = att;
        s_f2[HD + t] = s_p[t];
        cstf(fused + (size_t)b * 2 * HD + t, att);
        __syncthreads();

        int e = t & 7, ch = t >> 3;
        float gp = 0.f;
        #pragma unroll
        for (int j = 0; j < 16; ++j) {
            int d = ch * 16 + j;
            gp = fmaf(s_f2[d], gW[d * NE + e], gp);
        }
        s_red[t] = gp;
        __syncthreads();
        for (int off = 128; off >= 8; off >>= 1) {
            if (t < off) s_red[t] += s_red[t + off];
            __syncthreads();
        }
        if (t < NE) s_gate[t] = s_red[t] + gb[t];
        __syncthreads();
        if (t == 0) {
            float m = s_gate[0];
            for (int i = 1; i < NE; ++i) m = fmaxf(m, s_gate[i]);
            float ex[NE], ssum = 0.f;
            for (int i = 0; i < NE; ++i) { ex[i] = expf(s_gate[i] - m); ssum += ex[i]; }
            float pr[NE];
            for (int i = 0; i < NE; ++i) { pr[i] = ex[i] / ssum; cstf(probs + b * NE + i, pr[i]); }
            int i1 = 0;
            for (int i = 1; i < NE; ++i) if (pr[i] > pr[i1]) i1 = i;
            int i2 = (i1 == 0) ? 1 : 0;
            for (int i = 0; i < NE; ++i) if (i != i1 && pr[i] > pr[i2]) i2 = i;
            float p1 = pr[i1], p2 = pr[i2], s12 = p1 + p2;
            csti(sel + b * 2 + 0, i1);
            csti(sel + b * 2 + 1, i2);
            cstf(pn + b * 2 + 0, p1 / s12);
            cstf(pn + b * 2 + 1, p2 / s12);
        }
    }
    gsync(slots + 1 * NBLK, gen + 1, tb + 2u);

    // ---------------- P2: h1 = gelu(fused @ W1[e] + b1[e]) (256 blocks) -------
    {
        int e = bid >> 5, ct = bid & 31;
        float* s_f = smem + S_BIG;    // [32][520]
        float* s_w = smem + S_W;      // [128][16]
        stage16k(fused, s_f, t);
        int c = t & 15, rg = t >> 4, r0 = rg * 2, r1 = r0 + 1;
        float a0 = 0.f, a1 = 0.f, a2 = 0.f, a3 = 0.f;
        const float* W = W1 + (size_t)e * D2 * D2 + ct * 16;
        for (int k0 = 0; k0 < D2; k0 += 128) {
            __syncthreads();
            for (int i = t; i < 128 * 4; i += NTHR) {
                int kk = i >> 2, f = i & 3;
                *(float4*)&s_w[kk * 16 + f * 4] =
                    *(const float4*)(W + (size_t)(k0 + kk) * D2 + f * 4);
            }
            __syncthreads();
            #pragma unroll 8
            for (int kk = 0; kk < 128; kk += 2) {
                float w0 = s_w[kk * 16 + c], w1 = s_w[(kk + 1) * 16 + c];
                a0 = fmaf(s_f[r0 * 520 + k0 + kk], w0, a0);
                a1 = fmaf(s_f[r0 * 520 + k0 + kk + 1], w1, a1);
                a2 = fmaf(s_f[r1 * 520 + k0 + kk], w0, a2);
                a3 = fmaf(s_f[r1 * 520 + k0 + kk + 1], w1, a3);
            }
        }
        int col = ct * 16 + c;
        float bias = b1[e * D2 + col];
        cstf(h1 + ((size_t)e * NB + r0) * D2 + col, gelu_exact(a0 + a1 + bias));
        cstf(h1 + ((size_t)e * NB + r1) * D2 + col, gelu_exact(a2 + a3 + bias));
    }
    gsync(slots + 2 * NBLK, gen + 2, tb + 3u);

    // ---------------- P3: eo = h1 @ W2[e] + b2[e] (128 blocks) ----------------
    if (bid < 128) {
        int e = bid >> 4, ct = bid & 15;
        float* s_h = smem + S_BIG;
        float* s_w = smem + S_W;
        stage16k(h1 + (size_t)e * NB * D2, s_h, t);
        int c = t & 15, rg = t >> 4, r0 = rg * 2, r1 = r0 + 1;
        float a0 = 0.f, a1 = 0.f, a2 = 0.f, a3 = 0.f;
        const float* W = W2 + (size_t)e * D2 * HD + ct * 16;
        for (int k0 = 0; k0 < D2; k0 += 128) {
            __syncthreads();
            for (int i = t; i < 128 * 4; i += NTHR) {
                int kk = i >> 2, f = i & 3;
                *(float4*)&s_w[kk * 16 + f * 4] =
                    *(const float4*)(W + (size_t)(k0 + kk) * HD + f * 4);
            }
            __syncthreads();
            #pragma unroll 8
            for (int kk = 0; kk < 128; kk += 2) {
                float w0 = s_w[kk * 16 + c], w1 = s_w[(kk + 1) * 16 + c];
                a0 = fmaf(s_h[r0 * 520 + k0 + kk], w0, a0);
                a1 = fmaf(s_h[r0 * 520 + k0 + kk + 1], w1, a1);
                a2 = fmaf(s_h[r1 * 520 + k0 + kk], w0, a2);
                a3 = fmaf(s_h[r1 * 520 + k0 + kk + 1], w1, a3);
            }
        }
        int col = ct * 16 + c;
        float bias = b2[e * HD + col];
        cstf(eo + ((size_t)e * NB + r0) * HD + col, a0 + a1 + bias);
        cstf(eo + ((size_t)e * NB + r1) * HD + col, a2 + a3 + bias);
    }
    gsync(slots + 3 * NBLK, gen + 3, tb + 4u);

    // launch-token bump: safe — every block already read LC before barrier 1
    if (bid == 0 && t == 0)
        __hip_atomic_store(LC, s_lc + 1u, __ATOMIC_RELAXED, __HIP_MEMORY_SCOPE_AGENT);

    // ---------------- P4: gather/combine, LN, classifier, aux (32 blocks) -----
    if (bid < NB) {
        int b = bid;
        float* s_red = smem + S_RED;
        float* s_stats = smem + S_SMALL;
        int e0 = cldi(sel + b * 2 + 0), e1 = cldi(sel + b * 2 + 1);
        float p0 = cldf(pn + b * 2 + 0), p1 = cldf(pn + b * 2 + 1);
        float moe = p0 * cldf(eo + ((size_t)e0 * NB + b) * HD + t)
                  + p1 * cldf(eo + ((size_t)e1 * NB + b) * HD + t);

        s_red[t] = moe; __syncthreads();
        for (int off = 128; off > 0; off >>= 1) {
            if (t < off) s_red[t] += s_red[t + off];
            __syncthreads();
        }
        if (t == 0) s_stats[0] = s_red[0] * (1.f / HD);
        __syncthreads();
        float mu = s_stats[0];
        float d = moe - mu;

        s_red[t] = d * d; __syncthreads();
        for (int off = 128; off > 0; off >>= 1) {
            if (t < off) s_red[t] += s_red[t + off];
            __syncthreads();
        }
        if (t == 0) s_stats[1] = s_red[0] * (1.f / HD);
        __syncthreads();

        float xn = d * rsqrtf(s_stats[1] + 1e-5f);
        float y = fmaf(xn, lng[t], lnb[t]);

        s_red[t] = y * clsW[t * 2 + 0]; __syncthreads();
        for (int off = 128; off > 0; off >>= 1) {
            if (t < off) s_red[t] += s_red[t + off];
            __syncthreads();
        }
        if (t == 0) s_stats[2] = s_red[0] + clsb[0];
        __syncthreads();

        s_red[t] = y * clsW[t * 2 + 1]; __syncthreads();
        for (int off = 128; off > 0; off >>= 1) {
            if (t < off) s_red[t] += s_red[t + off];
            __syncthreads();
        }
        if (t == 0) {
            out[b * 2 + 0] = s_stats[2];
            out[b * 2 + 1] = s_red[0] + clsb[1];
        }

        if (bid == 0) {
            __syncthreads();
            s_red[t] = cldf(probs + t);
            __syncthreads();
            for (int off = 128; off >= 8; off >>= 1) {
                if (t < off) s_red[t] += s_red[t + off];
                __syncthreads();
            }
            if (t == 0) {
                float aux = 0.f;
                for (int e = 0; e < NE; ++e) {
                    float u = s_red[e] * (1.f / 32.f);
                    aux += u * logf(0.125f) - logf(u) * 0.125f;
                }
                out[64] = 0.1f * aux;
            }
        }
    }
}

extern "C" void kernel_launch(void* const* d_in, const int* in_sizes, int n_in,
                              void* d_out, int out_size, void* d_ws, size_t ws_size,
                              hipStream_t stream) {
    (void)in_sizes; (void)n_in; (void)out_size; (void)ws_size;
    const float* smiles = (const float*)d_in[2];
    const float* sW  = (const float*)d_in[7];
    const float* sb  = (const float*)d_in[8];
    const float* Wv  = (const float*)d_in[13];
    const float* bv  = (const float*)d_in[14];
    const float* Wo  = (const float*)d_in[15];
    const float* bo  = (const float*)d_in[16];
    const float* gW  = (const float*)d_in[17];
    const float* gb  = (const float*)d_in[18];
    const float* W1  = (const float*)d_in[19];
    const float* b1  = (const float*)d_in[20];
    const float* W2  = (const float*)d_in[21];
    const float* b2  = (const float*)d_in[22];
    const float* lng = (const float*)d_in[23];
    const float* lnb = (const float*)d_in[24];
    const float* cW  = (const float*)d_in[25];
    const float* cb  = (const float*)d_in[26];
    float* out = (float*)d_out;
    float* ws  = (float*)d_ws;

    float*    proj  = ws;                      // 8192
    float*    fused = ws + 8192;               // 16384
    float*    probs = ws + 24576;              // 256
    float*    pn    = ws + 24832;              // 64
    int*      sel   = (int*)(ws + 24896);      // 64
    float*    h1    = ws + 24960;              // 131072
    float*    eo    = ws + 156032;             // 65536
    unsigned* slots = (unsigned*)(ws + 221568);// 4*256 uints
    unsigned* LC    = (unsigned*)(ws + 222592);// 1 uint
    unsigned* gen   = (unsigned*)(ws + 222593);// 4 uints

    fused_all<<<NBLK, NTHR, 0, stream>>>(
        smiles, sW, sb, Wv, bv, Wo, bo, gW, gb, W1, b1, W2, b2,
        lng, lnb, cW, cb,
        proj, fused, probs, pn, sel, h1, eo, slots, gen, LC, out);
}

// Round 8
// 41.638 us; speedup vs baseline: 7.2853x; 1.3857x over previous
//
#include <hip/hip_runtime.h>
#include <math.h>

#define HD 256
#define SD 768
#define D2 512
#define NE 8
#define NB 32
#define NBLK 256
#define NTHR 256
#define SFP 516   // padded row stride for [32][512] staging (b128-aligned, 4-way worst)

typedef float f32x4 __attribute__((ext_vector_type(4)));
typedef unsigned u32x4 __attribute__((ext_vector_type(4)));

__device__ __forceinline__ float gelu_exact(float x) {
    return 0.5f * x * (1.0f + erff(x * 0.70710678118654752f));
}

// ---- Coherent (L2-bypassing) access for cross-block intermediates ----------
__device__ __forceinline__ void cstf(float* p, float v) {
    __hip_atomic_store(p, v, __ATOMIC_RELAXED, __HIP_MEMORY_SCOPE_AGENT);
}
__device__ __forceinline__ float cldf(const float* p) {
    return __hip_atomic_load(p, __ATOMIC_RELAXED, __HIP_MEMORY_SCOPE_AGENT);
}
__device__ __forceinline__ void csti(int* p, int v) {
    __hip_atomic_store(p, v, __ATOMIC_RELAXED, __HIP_MEMORY_SCOPE_AGENT);
}
__device__ __forceinline__ int cldi(const int* p) {
    return __hip_atomic_load(p, __ATOMIC_RELAXED, __HIP_MEMORY_SCOPE_AGENT);
}

// Bulk-stage 16KB global->LDS ([32][SFP] layout), 16 deep-pipelined coherent
// dwordx4 loads, one vmcnt drain, then LDS float4 writes (R6, verified).
__device__ __forceinline__ void stage16k(const float* __restrict__ gsrc,
                                         float* __restrict__ lds, int t)
{
    const f32x4* src = (const f32x4*)gsrc;
    f32x4 r[16];
    #pragma unroll
    for (int j = 0; j < 16; ++j) {
        const f32x4* p = src + (t + j * 256);
        asm volatile("global_load_dwordx4 %0, %1, off sc0 sc1"
                     : "=v"(r[j]) : "v"(p));
    }
    asm volatile("s_waitcnt vmcnt(0)" ::: "memory");
    __builtin_amdgcn_sched_barrier(0);
    #pragma unroll
    for (int j = 0; j < 16; ++j) {
        int q = t + j * 256;
        *(f32x4*)&lds[(q >> 7) * SFP + (q & 127) * 4] = r[j];
    }
}

// Hierarchical grid barrier (R7, verified): arrivals store slots[bid]; block0
// wave0 scans the 1KB slot array; publishes one `gen` word; others poll gen.
__device__ __forceinline__ void gsync(unsigned* slots, unsigned* gen,
                                      unsigned tok) {
    __syncthreads();   // drains vmcnt -> this block's sc1 stores are at L3
    const int t = threadIdx.x;
    if (t == 0)
        __hip_atomic_store(slots + blockIdx.x, tok, __ATOMIC_RELAXED,
                           __HIP_MEMORY_SCOPE_AGENT);
    if (blockIdx.x == 0) {
        if (t < 64) {
            const u32x4* p = (const u32x4*)slots + t;
            for (;;) {
                u32x4 v;
                asm volatile("global_load_dwordx4 %0, %1, off sc0 sc1\n\t"
                             "s_waitcnt vmcnt(0)"
                             : "=&v"(v) : "v"(p) : "memory");
                bool ok = (v[0] == tok) & (v[1] == tok) &
                          (v[2] == tok) & (v[3] == tok);
                if (__ballot(ok) == ~0ull) break;
                __builtin_amdgcn_s_sleep(1);
            }
            if (t == 0)
                __hip_atomic_store(gen, tok, __ATOMIC_RELAXED,
                                   __HIP_MEMORY_SCOPE_AGENT);
        }
    } else {
        if (t == 0) {
            while (__hip_atomic_load(gen, __ATOMIC_RELAXED,
                                     __HIP_MEMORY_SCOPE_AGENT) != tok)
                __builtin_amdgcn_s_sleep(1);
        }
    }
    __builtin_amdgcn_fence(__ATOMIC_ACQUIRE, "workgroup");
    __syncthreads();
}

// Shared-memory carve-up (floats)
#define S_F     0                    // 32*516 = 16512 (staging / P0 s_in / P1 vecs)
#define S_W     16512                // 512*16 = 8192
#define S_R2    (16512 + 8192)       // 2048 (k-split partials; P1 s_acc)
#define S_RED   (16512 + 8192 + 2048)        // 256
#define S_SMALL (16512 + 8192 + 2048 + 256)  // 16
#define SMEM_F  (16512 + 8192 + 2048 + 256 + 16)   // 27024 fl = 108,096 B

__global__ __launch_bounds__(256) void fused_all(
    const float* __restrict__ smiles,
    const float* __restrict__ sW, const float* __restrict__ sb,
    const float* __restrict__ Wv, const float* __restrict__ bv,
    const float* __restrict__ Wo, const float* __restrict__ bo,
    const float* __restrict__ gW, const float* __restrict__ gb,
    const float* __restrict__ W1, const float* __restrict__ b1,
    const float* __restrict__ W2, const float* __restrict__ b2,
    const float* __restrict__ lng, const float* __restrict__ lnb,
    const float* __restrict__ clsW, const float* __restrict__ clsb,
    float* __restrict__ proj, float* __restrict__ fused,
    float* __restrict__ probs, float* __restrict__ pn,
    int* __restrict__ sel, float* __restrict__ h1,
    float* __restrict__ eo, unsigned* __restrict__ slots,
    unsigned* __restrict__ gen, unsigned* __restrict__ LC,
    float* __restrict__ out)
{
    __shared__ __align__(16) float smem[SMEM_F];
    __shared__ unsigned s_lc;
    const int bid = blockIdx.x, t = threadIdx.x;

    if (t == 0)
        s_lc = __hip_atomic_load(LC, __ATOMIC_RELAXED, __HIP_MEMORY_SCOPE_AGENT);
    __syncthreads();
    const unsigned tb = s_lc * 2654435761u;

    // ---------------- P0: proj = smiles @ sW + sb (256 blocks) ----------------
    {
        int r = bid >> 3, sl = bid & 7;
        float* s_in = smem + S_F;                   // 768
        float* s_red = smem + S_RED;
        const float* srow = smiles + (size_t)r * SD;
        for (int i = t; i < SD / 4; i += NTHR)
            ((float4*)s_in)[i] = ((const float4*)srow)[i];
        __syncthreads();
        int c = t & 31, kq = t >> 5;                // 32 cols x 8 k-quadrants
        float acc = 0.f;
        const float* wp = sW + (size_t)(kq * 96) * HD + sl * 32 + c;
        #pragma unroll 8
        for (int k = 0; k < 96; ++k)
            acc = fmaf(s_in[kq * 96 + k], wp[(size_t)k * HD], acc);
        s_red[t] = acc;
        __syncthreads();
        if (t < 32) {
            float s = 0.f;
            #pragma unroll
            for (int q = 0; q < 8; ++q) s += s_red[q * 32 + t];
            int col = sl * 32 + t;
            s += sb[col];
            cstf(proj + r * HD + col, s);
            cstf(fused + (size_t)r * 2 * HD + HD + col, s);   // 2nd half = proj
        }
    }
    gsync(slots + 0 * NBLK, gen + 0, tb + 1u);

    // ---------------- P1: v -> attended -> gate/top2 (32 blocks) --------------
    if (bid < NB) {
        int b = bid;
        float* s_p   = smem + S_F;           // 256
        float* s_v   = smem + S_F + 256;     // 256
        float* s_f2  = smem + S_F + 512;     // 512
        float* s_acc = smem + S_R2;          // 1024
        float* s_red = smem + S_RED;
        float* s_gate = smem + S_SMALL;
        s_p[t] = cldf(proj + b * HD + t);
        __syncthreads();
        int ks = t >> 6, cg = t & 63;        // 4 k-splits x 64 col-quads

        f32x4 av = {0.f, 0.f, 0.f, 0.f};
        #pragma unroll 16
        for (int kk = 0; kk < 64; ++kk) {
            int k = ks * 64 + kk;
            f32x4 w = *(const f32x4*)(Wv + (size_t)k * HD + cg * 4);
            av += s_p[k] * w;
        }
        *(f32x4*)&s_acc[ks * 256 + cg * 4] = av;
        __syncthreads();
        s_v[t] = s_acc[t] + s_acc[256 + t] + s_acc[512 + t] + s_acc[768 + t]
               + bv[t];
        __syncthreads();

        f32x4 ao = {0.f, 0.f, 0.f, 0.f};
        #pragma unroll 16
        for (int kk = 0; kk < 64; ++kk) {
            int k = ks * 64 + kk;
            f32x4 w = *(const f32x4*)(Wo + (size_t)k * HD + cg * 4);
            ao += s_v[k] * w;
        }
        *(f32x4*)&s_acc[ks * 256 + cg * 4] = ao;
        __syncthreads();
        float att = s_acc[t] + s_acc[256 + t] + s_acc[512 + t] + s_acc[768 + t]
                  + bo[t];
        s_f2[t] = att;
        s_f2[HD + t] = s_p[t];
        cstf(fused + (size_t)b * 2 * HD + t, att);
        __syncthreads();

        int e = t & 7, ch = t >> 3;
        float gp = 0.f;
        #pragma unroll
        for (int j = 0; j < 16; ++j) {
            int d = ch * 16 + j;
            gp = fmaf(s_f2[d], gW[d * NE + e], gp);
        }
        s_red[t] = gp;
        __syncthreads();
        for (int off = 128; off >= 8; off >>= 1) {
            if (t < off) s_red[t] += s_red[t + off];
            __syncthreads();
        }
        if (t < NE) s_gate[t] = s_red[t] + gb[t];
        __syncthreads();
        if (t == 0) {
            float m = s_gate[0];
            for (int i = 1; i < NE; ++i) m = fmaxf(m, s_gate[i]);
            float ex[NE], ssum = 0.f;
            for (int i = 0; i < NE; ++i) { ex[i] = expf(s_gate[i] - m); ssum += ex[i]; }
            float pr[NE];
            for (int i = 0; i < NE; ++i) { pr[i] = ex[i] / ssum; cstf(probs + b * NE + i, pr[i]); }
            int i1 = 0;
            for (int i = 1; i < NE; ++i) if (pr[i] > pr[i1]) i1 = i;
            int i2 = (i1 == 0) ? 1 : 0;
            for (int i = 0; i < NE; ++i) if (i != i1 && pr[i] > pr[i2]) i2 = i;
            float p1 = pr[i1], p2 = pr[i2], s12 = p1 + p2;
            csti(sel + b * 2 + 0, i1);
            csti(sel + b * 2 + 1, i2);
            cstf(pn + b * 2 + 0, p1 / s12);
            cstf(pn + b * 2 + 1, p2 / s12);
        }
    }
    gsync(slots + 1 * NBLK, gen + 1, tb + 2u);

    // ------- P2: h1 = gelu(fused @ W1[e] + b1[e]) (256 blocks, reg-tiled) -----
    {
        int e = bid >> 5, ct = bid & 31;
        float* s_f  = smem + S_F;    // [32][516]
        float* s_w  = smem + S_W;    // [512][16]
        float* s_r2 = smem + S_R2;   // [512 outs][4 ks]
        stage16k(fused, s_f, t);
        {
            const float* Wb = W1 + (size_t)e * D2 * D2 + ct * 16;
            #pragma unroll
            for (int j = 0; j < 8; ++j) {
                int q = t + j * 256;
                int k = q >> 2, c4 = (q & 3) * 4;
                *(float4*)&s_w[k * 16 + c4] =
                    *(const float4*)(Wb + (size_t)k * D2 + c4);
            }
        }
        __syncthreads();
        int ks = t >> 6, l = t & 63;
        int rp = l >> 2, c4g = l & 3;
        int r0 = rp * 2, r1 = r0 + 1;
        const float* fr0 = s_f + r0 * SFP;
        const float* fr1 = s_f + r1 * SFP;
        const float* wb = s_w + c4g * 4;
        f32x4 a0 = {0.f, 0.f, 0.f, 0.f}, a1 = {0.f, 0.f, 0.f, 0.f};
        #pragma unroll 4
        for (int kq = 0; kq < 32; ++kq) {
            int k = ks * 128 + kq * 4;
            f32x4 w0 = *(const f32x4*)&wb[(k + 0) * 16];
            f32x4 w1 = *(const f32x4*)&wb[(k + 1) * 16];
            f32x4 w2 = *(const f32x4*)&wb[(k + 2) * 16];
            f32x4 w3 = *(const f32x4*)&wb[(k + 3) * 16];
            f32x4 f0 = *(const f32x4*)&fr0[k];
            f32x4 f1 = *(const f32x4*)&fr1[k];
            a0 += f0[0] * w0 + f0[1] * w1 + f0[2] * w2 + f0[3] * w3;
            a1 += f1[0] * w0 + f1[1] * w1 + f1[2] * w2 + f1[3] * w3;
        }
        int cl = c4g * 4;
        #pragma unroll
        for (int j = 0; j < 4; ++j) {
            s_r2[(r0 * 16 + cl + j) * 4 + ks] = a0[j];
            s_r2[(r1 * 16 + cl + j) * 4 + ks] = a1[j];
        }
        __syncthreads();
        #pragma unroll
        for (int o = 0; o < 2; ++o) {
            int outi = t * 2 + o;
            f32x4 p = *(const f32x4*)&s_r2[outi * 4];
            int r = outi >> 4, cl2 = outi & 15;
            int col = ct * 16 + cl2;
            float v = p[0] + p[1] + p[2] + p[3] + b1[e * D2 + col];
            cstf(h1 + ((size_t)e * NB + r) * D2 + col, gelu_exact(v));
        }
    }
    gsync(slots + 2 * NBLK, gen + 2, tb + 3u);

    // ------- P3: eo = h1 @ W2[e] + b2[e] (128 blocks, reg-tiled) --------------
    if (bid < 128) {
        int e = bid >> 4, ct = bid & 15;
        float* s_h  = smem + S_F;
        float* s_w  = smem + S_W;
        float* s_r2 = smem + S_R2;
        stage16k(h1 + (size_t)e * NB * D2, s_h, t);
        {
            const float* Wb = W2 + (size_t)e * D2 * HD + ct * 16;
            #pragma unroll
            for (int j = 0; j < 8; ++j) {
                int q = t + j * 256;
                int k = q >> 2, c4 = (q & 3) * 4;
                *(float4*)&s_w[k * 16 + c4] =
                    *(const float4*)(Wb + (size_t)k * HD + c4);
            }
        }
        __syncthreads();
        int ks = t >> 6, l = t & 63;
        int rp = l >> 2, c4g = l & 3;
        int r0 = rp * 2, r1 = r0 + 1;
        const float* fr0 = s_h + r0 * SFP;
        const float* fr1 = s_h + r1 * SFP;
        const float* wb = s_w + c4g * 4;
        f32x4 a0 = {0.f, 0.f, 0.f, 0.f}, a1 = {0.f, 0.f, 0.f, 0.f};
        #pragma unroll 4
        for (int kq = 0; kq < 32; ++kq) {
            int k = ks * 128 + kq * 4;
            f32x4 w0 = *(const f32x4*)&wb[(k + 0) * 16];
            f32x4 w1 = *(const f32x4*)&wb[(k + 1) * 16];
            f32x4 w2 = *(const f32x4*)&wb[(k + 2) * 16];
            f32x4 w3 = *(const f32x4*)&wb[(k + 3) * 16];
            f32x4 f0 = *(const f32x4*)&fr0[k];
            f32x4 f1 = *(const f32x4*)&fr1[k];
            a0 += f0[0] * w0 + f0[1] * w1 + f0[2] * w2 + f0[3] * w3;
            a1 += f1[0] * w0 + f1[1] * w1 + f1[2] * w2 + f1[3] * w3;
        }
        int cl = c4g * 4;
        #pragma unroll
        for (int j = 0; j < 4; ++j) {
            s_r2[(r0 * 16 + cl + j) * 4 + ks] = a0[j];
            s_r2[(r1 * 16 + cl + j) * 4 + ks] = a1[j];
        }
        __syncthreads();
        #pragma unroll
        for (int o = 0; o < 2; ++o) {
            int outi = t * 2 + o;
            f32x4 p = *(const f32x4*)&s_r2[outi * 4];
            int r = outi >> 4, cl2 = outi & 15;
            int col = ct * 16 + cl2;
            float v = p[0] + p[1] + p[2] + p[3] + b2[e * HD + col];
            cstf(eo + ((size_t)e * NB + r) * HD + col, v);
        }
    }
    gsync(slots + 3 * NBLK, gen + 3, tb + 4u);

    // launch-token bump: safe — every block already read LC before barrier 1
    if (bid == 0 && t == 0)
        __hip_atomic_store(LC, s_lc + 1u, __ATOMIC_RELAXED, __HIP_MEMORY_SCOPE_AGENT);

    // ---------------- P4: gather/combine, LN, classifier, aux (32 blocks) -----
    if (bid < NB) {
        int b = bid;
        float* s_red = smem + S_RED;
        float* s_stats = smem + S_SMALL;
        int e0 = cldi(sel + b * 2 + 0), e1 = cldi(sel + b * 2 + 1);
        float p0 = cldf(pn + b * 2 + 0), p1 = cldf(pn + b * 2 + 1);
        float moe = p0 * cldf(eo + ((size_t)e0 * NB + b) * HD + t)
                  + p1 * cldf(eo + ((size_t)e1 * NB + b) * HD + t);

        s_red[t] = moe; __syncthreads();
        for (int off = 128; off > 0; off >>= 1) {
            if (t < off) s_red[t] += s_red[t + off];
            __syncthreads();
        }
        if (t == 0) s_stats[0] = s_red[0] * (1.f / HD);
        __syncthreads();
        float mu = s_stats[0];
        float d = moe - mu;

        s_red[t] = d * d; __syncthreads();
        for (int off = 128; off > 0; off >>= 1) {
            if (t < off) s_red[t] += s_red[t + off];
            __syncthreads();
        }
        if (t == 0) s_stats[1] = s_red[0] * (1.f / HD);
        __syncthreads();

        float xn = d * rsqrtf(s_stats[1] + 1e-5f);
        float y = fmaf(xn, lng[t], lnb[t]);

        s_red[t] = y * clsW[t * 2 + 0]; __syncthreads();
        for (int off = 128; off > 0; off >>= 1) {
            if (t < off) s_red[t] += s_red[t + off];
            __syncthreads();
        }
        if (t == 0) s_stats[2] = s_red[0] + clsb[0];
        __syncthreads();

        s_red[t] = y * clsW[t * 2 + 1]; __syncthreads();
        for (int off = 128; off > 0; off >>= 1) {
            if (t < off) s_red[t] += s_red[t + off];
            __syncthreads();
        }
        if (t == 0) {
            out[b * 2 + 0] = s_stats[2];
            out[b * 2 + 1] = s_red[0] + clsb[1];
        }

        if (bid == 0) {
            __syncthreads();
            s_red[t] = cldf(probs + t);
            __syncthreads();
            for (int off = 128; off >= 8; off >>= 1) {
                if (t < off) s_red[t] += s_red[t + off];
                __syncthreads();
            }
            if (t == 0) {
                float aux = 0.f;
                for (int e = 0; e < NE; ++e) {
                    float u = s_red[e] * (1.f / 32.f);
                    aux += u * logf(0.125f) - logf(u) * 0.125f;
                }
                out[64] = 0.1f * aux;
            }
        }
    }
}

extern "C" void kernel_launch(void* const* d_in, const int* in_sizes, int n_in,
                              void* d_out, int out_size, void* d_ws, size_t ws_size,
                              hipStream_t stream) {
    (void)in_sizes; (void)n_in; (void)out_size; (void)ws_size;
    const float* smiles = (const float*)d_in[2];
    const float* sW  = (const float*)d_in[7];
    const float* sb  = (const float*)d_in[8];
    const float* Wv  = (const float*)d_in[13];
    const float* bv  = (const float*)d_in[14];
    const float* Wo  = (const float*)d_in[15];
    const float* bo  = (const float*)d_in[16];
    const float* gW  = (const float*)d_in[17];
    const float* gb  = (const float*)d_in[18];
    const float* W1  = (const float*)d_in[19];
    const float* b1  = (const float*)d_in[20];
    const float* W2  = (const float*)d_in[21];
    const float* b2  = (const float*)d_in[22];
    const float* lng = (const float*)d_in[23];
    const float* lnb = (const float*)d_in[24];
    const float* cW  = (const float*)d_in[25];
    const float* cb  = (const float*)d_in[26];
    float* out = (float*)d_out;
    float* ws  = (float*)d_ws;

    float*    proj  = ws;                      // 8192
    float*    fused = ws + 8192;               // 16384
    float*    probs = ws + 24576;              // 256
    float*    pn    = ws + 24832;              // 64
    int*      sel   = (int*)(ws + 24896);      // 64
    float*    h1    = ws + 24960;              // 131072
    float*    eo    = ws + 156032;             // 65536
    unsigned* slots = (unsigned*)(ws + 221568);// 4*256 uints
    unsigned* LC    = (unsigned*)(ws + 222592);// 1 uint
    unsigned* gen   = (unsigned*)(ws + 222593);// 4 uints

    fused_all<<<NBLK, NTHR, 0, stream>>>(
        smiles, sW, sb, Wv, bv, Wo, bo, gW, gb, W1, b1, W2, b2,
        lng, lnb, cW, cb,
        proj, fused, probs, pn, sel, h1, eo, slots, gen, LC, out);
}